// Round 18
// baseline (2776.824 us; speedup 1.0000x reference)
//
#include <hip/hip_runtime.h>
#include <hip/hip_bf16.h>
#include <math.h>

// =====================================================================
// SwinTransformerBlock forward, round 24: T14 async-STAGE prefetch.
//   Conv staging split into {issue global loads -> regs} before the
//   compute phase of the PREVIOUS chunk and {cvt+LDS write} after its
//   barrier: chunk i+1's HBM latency hides under chunk i's MFMAs
//   (old structure exposed ~6K cycles/chunk of load latency serially).
//   Registers: mfconv3 +40 VGPR (NB=5x8), mfconv K=3 +24 -- LDS caps
//   occupancy at 3 blocks/CU so the VGPRs are free. Arithmetic
//   bit-identical to round 22. attn/mlpmf/xb1x1 unchanged.
// Workspace: as round 16.
// =====================================================================

#define HW  50176
#define WID 224

typedef unsigned short ushortT;
typedef __attribute__((ext_vector_type(8))) short bf8_t;
typedef __attribute__((ext_vector_type(4))) short bf4_t;
typedef __attribute__((ext_vector_type(4))) float f4_t;

__device__ __forceinline__ ushortT f2bf(float v) {
    __hip_bfloat16 h = __float2bfloat16(v);   // HW cvt, round-to-nearest-even
    ushortT u; __builtin_memcpy(&u, &h, 2); return u;
}
__device__ __forceinline__ float bf2f(ushortT h) {
    union { float f; unsigned int u; } c; c.u = ((unsigned int)h) << 16;
    return c.f;
}
__device__ __forceinline__ void cvt8(const float* xv, bf8_t& hh, bf8_t& ll) {
    #pragma unroll
    for (int i = 0; i < 8; ++i) {
        ushortT hi = f2bf(xv[i]);
        hh[i] = (short)hi;
        ll[i] = (short)f2bf(xv[i] - bf2f(hi));
    }
}

// ---------------------------------------------------------------------
// Pre-pack conv weights (OIHW f32) into B-fragment order bf16 hi/lo.
// ---------------------------------------------------------------------
__global__ __launch_bounds__(256) void packw(
    const float* __restrict__ w, ushortT* __restrict__ dst,
    int K, int IC, int OC, int total)
{
    int e = blockIdx.x * 256 + threadIdx.x;
    if (e >= total) return;
    int KK = K * K;
    int kk = e % KK; int rem = e / KK;
    int ic = rem % IC; int oc = rem / IC;
    float v = w[e];
    ushortT hi = f2bf(v);
    ushortT lo = f2bf(v - bf2f(hi));
    int g = oc >> 6, oc64 = oc & 63;
    int ic32 = ic >> 5, icin = ic & 31, kb = icin >> 3, ii = icin & 7;
    int nch = KK * (IC / 32);
    int chunk = ic32 * KK + kk;
    size_t base = ((size_t)(g * nch + chunk)) * 4096;
    dst[base + (kb * 64 + oc64) * 8 + ii] = hi;
    dst[base + 2048 + (kb * 64 + oc64) * 8 + ii] = lo;
}

// ---------------------------------------------------------------------
// Pack a [OC][K] f32 matrix into 16x16x32 A-fragment order (hi/lo).
// ---------------------------------------------------------------------
__global__ __launch_bounds__(256) void packa32(
    const float* __restrict__ w, ushortT* __restrict__ dst, int K, int total)
{
    int e = blockIdx.x * 256 + threadIdx.x;
    if (e >= total) return;
    int f = e >> 9, r = e & 511, ln = r >> 3, i = r & 7;
    int nk = K >> 5;
    int o = f / nk, ks = f % nk;
    int c = ln & 15, gg = ln >> 4;
    float v = w[(size_t)(o * 16 + c) * K + ks * 32 + gg * 8 + i];
    ushortT hi = f2bf(v);
    dst[(size_t)f * 1024 + ln * 8 + i] = hi;
    dst[(size_t)f * 1024 + 512 + ln * 8 + i] = f2bf(v - bf2f(hi));
}

// ---------------------------------------------------------------------
// Pack a [OC][K] f32 matrix into 16x16x16 A-fragment order (hi/lo).
// ---------------------------------------------------------------------
__global__ __launch_bounds__(256) void packa16(
    const float* __restrict__ w, ushortT* __restrict__ dst, int K, int total)
{
    int e = blockIdx.x * 256 + threadIdx.x;
    if (e >= total) return;
    int f = e >> 8, r = e & 255, ln = r >> 2, i = r & 3;
    int nk = K >> 4;
    int o = f / nk, n = f % nk;
    int c = ln & 15, gg = ln >> 4;
    float v = w[(size_t)(o * 16 + c) * K + n * 16 + gg * 4 + i];
    ushortT hi = f2bf(v);
    dst[(size_t)f * 512 + ln * 4 + i] = hi;
    dst[(size_t)f * 512 + 256 + ln * 4 + i] = f2bf(v - bf2f(hi));
}

// ---------------------------------------------------------------------
// One conv's MFMA pass over the shared staged tile (origin -3, TWd=22).
// Copy-free B ping-pong: pairs of kk with two named register sets.
// ---------------------------------------------------------------------
template<int K>
__device__ __forceinline__ void convpass(
    const ushortT* __restrict__ wq, const ushortT* __restrict__ sm,
    int wv, int lc, int kb, f4_t (&ac)[2][4])
{
    constexpr int off = 3 - K / 2;
    constexpr int INSH = 14 * 22 * 40;
    constexpr int KK = K * K;              // odd: 9 / 25 / 49
    const int boff = (kb * 64 + lc) * 8;

    bf8_t bA[4], lA[4], bB[4], lB[4];
    #pragma unroll
    for (int n = 0; n < 4; ++n) {
        bA[n] = *(const bf8_t*)(wq + boff + n * 128);
        lA[n] = *(const bf8_t*)(wq + 2048 + boff + n * 128);
    }
    auto domfma = [&](int kk, bf8_t (&bh)[4], bf8_t (&bl)[4]) {
        const int ky = kk / K, kx = kk % K;
        #pragma unroll
        for (int m = 0; m < 2; ++m) {
            const int row = 2 * wv + m + ky + off;
            const int col = lc + kx + off;
            const ushortT* ab = sm + (row * 22 + col) * 40 + kb * 8;
            bf8_t Ah = *(const bf8_t*)ab;
            bf8_t Al = *(const bf8_t*)(ab + INSH);
            #pragma unroll
            for (int n = 0; n < 4; ++n) {
                ac[m][n] = __builtin_amdgcn_mfma_f32_16x16x32_bf16(Ah, bh[n], ac[m][n], 0, 0, 0);
                ac[m][n] = __builtin_amdgcn_mfma_f32_16x16x32_bf16(Ah, bl[n], ac[m][n], 0, 0, 0);
                ac[m][n] = __builtin_amdgcn_mfma_f32_16x16x32_bf16(Al, bh[n], ac[m][n], 0, 0, 0);
            }
        }
    };
    #pragma unroll 1
    for (int kk = 0; kk + 2 <= KK; kk += 2) {
        const ushortT* w1 = wq + (size_t)(kk + 1) * 4096;
        #pragma unroll
        for (int n = 0; n < 4; ++n) {
            bB[n] = *(const bf8_t*)(w1 + boff + n * 128);
            lB[n] = *(const bf8_t*)(w1 + 2048 + boff + n * 128);
        }
        domfma(kk, bA, lA);
        const ushortT* w2 = wq + (size_t)(kk + 2) * 4096;   // kk+2 <= KK-1
        #pragma unroll
        for (int n = 0; n < 4; ++n) {
            bA[n] = *(const bf8_t*)(w2 + boff + n * 128);
            lA[n] = *(const bf8_t*)(w2 + 2048 + boff + n * 128);
        }
        domfma(kk + 1, bB, lB);
    }
    domfma(KK - 1, bA, lA);
}

// ---------------------------------------------------------------------
// Fused c1(3x3)+c2(5x5)+c3(7x7) conv, IC=64, OC=64 each, relu, NCHW out.
// Grid: (14, 28, CS). Block 256 = 4 waves. Direct float4 epilogue.
// T14: chunk-1 loads issued to regs before chunk-0 compute.
// ---------------------------------------------------------------------
__global__ __launch_bounds__(256, 4) void mfconv3(
    const float* __restrict__ in,
    const ushortT* __restrict__ w1p, const ushortT* __restrict__ w2p,
    const ushortT* __restrict__ w3p,
    const float* __restrict__ b1, const float* __restrict__ b2,
    const float* __restrict__ b3,
    float* __restrict__ out, int inStride, int outStride)
{
    constexpr int TWd = 22, THd = 14, ICP = 40;
    constexpr int INSH = THd * TWd * ICP;      // 12320
    constexpr int E = THd * TWd * 32;          // 9856
    constexpr int NB = (E + 2047) / 2048;      // 5
    __shared__ __align__(16) ushortT smem_u[2 * INSH];

    const int t = threadIdx.x, lane = t & 63, wv = t >> 6;
    const int lc = lane & 15, kb = lane >> 4;
    const int img = blockIdx.z;
    const int x0 = blockIdx.x * 16, y0 = blockIdx.y * 8;
    const float* inb = in + (size_t)img * inStride;

    f4_t acc1[2][4], acc2[2][4], acc3[2][4];
    {
        #pragma unroll
        for (int n = 0; n < 4; ++n) {
            float z1 = b1[n * 16 + lc], z2 = b2[n * 16 + lc], z3 = b3[n * 16 + lc];
            #pragma unroll
            for (int m = 0; m < 2; ++m) {
                acc1[m][n] = (f4_t){z1, z1, z1, z1};
                acc2[m][n] = (f4_t){z2, z2, z2, z2};
                acc3[m][n] = (f4_t){z3, z3, z3, z3};
            }
        }
    }

    float vreg[NB][8];
    auto loadChunk = [&](int ic32) {
        #pragma unroll
        for (int b = 0; b < NB; ++b)
            #pragma unroll
            for (int u = 0; u < 8; ++u) {
                int i = b * 2048 + u * 256 + t;
                vreg[b][u] = 0.f;
                if (i < E) {
                    int icn = i / (THd * TWd);
                    int px  = i % (THd * TWd);
                    int ty = px / TWd, tx = px % TWd;
                    int gy = y0 + ty - 3, gx = x0 + tx - 3;
                    if (gy >= 0 && gy < WID && gx >= 0 && gx < WID)
                        vreg[b][u] = inb[(size_t)(ic32 * 32 + icn) * HW + gy * WID + gx];
                }
            }
    };
    auto writeChunk = [&]() {
        #pragma unroll
        for (int b = 0; b < NB; ++b)
            #pragma unroll
            for (int u = 0; u < 8; ++u) {
                int i = b * 2048 + u * 256 + t;
                if (i < E) {
                    int icn = i / (THd * TWd);
                    int px  = i % (THd * TWd);
                    ushortT hi = f2bf(vreg[b][u]);
                    smem_u[px * ICP + icn] = hi;
                    smem_u[INSH + px * ICP + icn] = f2bf(vreg[b][u] - bf2f(hi));
                }
            }
    };

    // ---- chunk 0: load+write, then prefetch chunk 1 under compute ----
    loadChunk(0);
    writeChunk();
    __syncthreads();
    loadChunk(1);      // loads in flight across the MFMA phase below
    convpass<3>(w1p, smem_u, wv, lc, kb, acc1);
    convpass<5>(w2p, smem_u, wv, lc, kb, acc2);
    convpass<7>(w3p, smem_u, wv, lc, kb, acc3);
    __syncthreads();
    // ---- chunk 1 ----
    writeChunk();
    __syncthreads();
    convpass<3>(w1p + (size_t) 9 * 4096, smem_u, wv, lc, kb, acc1);
    convpass<5>(w2p + (size_t)25 * 4096, smem_u, wv, lc, kb, acc2);
    convpass<7>(w3p + (size_t)49 * 4096, smem_u, wv, lc, kb, acc3);

    // ---- epilogue: relu + DIRECT float4 NCHW store (no LDS, no bar) ----
    // D layout: oc = n*16+lc, px(x) = kb*4+j (j contiguous), y = y0+2wv+m.
    #pragma unroll
    for (int c = 0; c < 3; ++c) {
        float* ob0 = out + (size_t)img * outStride + (size_t)(c * 64) * HW;
        #pragma unroll
        for (int m = 0; m < 2; ++m) {
            const int y = y0 + 2 * wv + m;
            #pragma unroll
            for (int n = 0; n < 4; ++n) {
                f4_t v = (c == 0) ? acc1[m][n] : (c == 1) ? acc2[m][n] : acc3[m][n];
                float4 st = { fmaxf(v[0], 0.f), fmaxf(v[1], 0.f),
                              fmaxf(v[2], 0.f), fmaxf(v[3], 0.f) };
                *(float4*)&ob0[(size_t)(n * 16 + lc) * HW + (size_t)y * WID + x0 + kb * 4] = st;
            }
        }
    }
}

// ---------------------------------------------------------------------
// MFMA conv. Template: K, IC, OC, ACT(1 relu, 2 sigmoid(relu)), CAT,
// LNRM, NHWCOUT. Grid: (14, 28, CS*OC/64). Block 256 = 4 waves.
// T14 prefetch: chunk i+1 loads issued to regs before chunk i compute.
// ---------------------------------------------------------------------
template<int K, int IC, int OC, int ACT, bool CAT, bool LNRM, bool NHWCOUT>
__global__ __launch_bounds__(256, 4) void mfconv(
    const float* __restrict__ in, const float* __restrict__ in2,
    const ushortT* __restrict__ wpk, const float* __restrict__ bias,
    const float* __restrict__ mu, const float* __restrict__ rs,
    const float* __restrict__ lng, const float* __restrict__ lnb,
    float* __restrict__ out, int inStride, int outStride)
{
    constexpr int P = K / 2, TWd = 16 + K - 1, THd = 8 + K - 1, ICP = 40;
    constexpr int OCG = OC / 64, KK = K * K, NCH = KK * (IC / 32);
    constexpr int NC = IC / 32;
    constexpr int INSH = THd * TWd * ICP;
    constexpr int E = THd * TWd * 32;
    constexpr int NB = (E + 2047) / 2048;
    constexpr int SMU = (2 * INSH > 10240) ? 2 * INSH : 10240;
    __shared__ __align__(16) ushortT smem_u[SMU];
    float* pool = (float*)smem_u;

    const int t = threadIdx.x, lane = t & 63, wv = t >> 6;
    const int lc = lane & 15, kb = lane >> 4;
    const int img = blockIdx.z / OCG, g = blockIdx.z % OCG;
    const int x0 = blockIdx.x * 16, y0 = blockIdx.y * 8;
    const float* inb  = in + (size_t)img * inStride;
    const float* in2b = CAT ? (in2 + (size_t)img * inStride) : nullptr;
    const int imgPixBase = img * HW;
    const ushortT* wq0 = wpk + (size_t)g * NCH * 4096;

    f4_t acc[2][4];
    {
        float bz0 = bias[g * 64 +  0 + lc];
        float bz1 = bias[g * 64 + 16 + lc];
        float bz2 = bias[g * 64 + 32 + lc];
        float bz3 = bias[g * 64 + 48 + lc];
        #pragma unroll
        for (int m = 0; m < 2; ++m) {
            acc[m][0] = (f4_t){bz0, bz0, bz0, bz0};
            acc[m][1] = (f4_t){bz1, bz1, bz1, bz1};
            acc[m][2] = (f4_t){bz2, bz2, bz2, bz2};
            acc[m][3] = (f4_t){bz3, bz3, bz3, bz3};
        }
    }
    const int aoff = lc * ICP + kb * 8;
    const int boff = (kb * 64 + lc) * 8;

    float vreg[NB][8];
    auto loadChunk = [&](int ic32) {
        #pragma unroll
        for (int b = 0; b < NB; ++b)
            #pragma unroll
            for (int u = 0; u < 8; ++u) {
                int i = b * 2048 + u * 256 + t;
                vreg[b][u] = 0.f;
                if (i < E) {
                    int icn = i / (THd * TWd);
                    int px  = i % (THd * TWd);
                    int ty = px / TWd, tx = px % TWd;
                    int gy = y0 + ty - P, gx = x0 + tx - P;
                    int ic = ic32 * 32 + icn;
                    if (gy >= 0 && gy < WID && gx >= 0 && gx < WID) {
                        const float* s;
                        if (CAT) s = (ic < 64) ? (inb + (size_t)ic * HW)
                                               : (in2b + (size_t)(ic - 64) * HW);
                        else     s = inb + (size_t)ic * HW;
                        float vv = s[gy * WID + gx];
                        if (LNRM) {
                            int p = imgPixBase + gy * WID + gx;
                            vv = (vv - mu[p]) * rs[p] * lng[ic] + lnb[ic];
                        }
                        vreg[b][u] = vv;
                    }
                }
            }
    };
    auto writeChunk = [&]() {
        #pragma unroll
        for (int b = 0; b < NB; ++b)
            #pragma unroll
            for (int u = 0; u < 8; ++u) {
                int i = b * 2048 + u * 256 + t;
                if (i < E) {
                    int icn = i / (THd * TWd);
                    int px  = i % (THd * TWd);
                    ushortT hi = f2bf(vreg[b][u]);
                    smem_u[px * ICP + icn] = hi;
                    smem_u[INSH + px * ICP + icn] = f2bf(vreg[b][u] - bf2f(hi));
                }
            }
    };

    loadChunk(0);
    #pragma unroll 1
    for (int ic32 = 0; ic32 < NC; ++ic32) {
        writeChunk();
        __syncthreads();
        if (ic32 + 1 < NC) loadChunk(ic32 + 1);   // in flight across MFMAs
        const ushortT* wqb = wq0 + (size_t)(ic32 * KK) * 4096;
        bf8_t bA[4], lA[4], bB[4], lB[4];
        #pragma unroll
        for (int n = 0; n < 4; ++n) {
            bA[n] = *(const bf8_t*)(wqb + boff + n * 128);
            lA[n] = *(const bf8_t*)(wqb + 2048 + boff + n * 128);
        }
        auto domfma = [&](int kk, bf8_t (&bh)[4], bf8_t (&bl)[4]) {
            const int ky = kk / K, kx = kk % K;
            #pragma unroll
            for (int m = 0; m < 2; ++m) {
                const int row = 2 * wv + m + ky;
                const ushortT* ab = smem_u + (row * TWd + kx) * ICP + aoff;
                bf8_t Ah = *(const bf8_t*)ab;
                bf8_t Al = *(const bf8_t*)(ab + INSH);
                #pragma unroll
                for (int n = 0; n < 4; ++n) {
                    acc[m][n] = __builtin_amdgcn_mfma_f32_16x16x32_bf16(Ah, bh[n], acc[m][n], 0, 0, 0);
                    acc[m][n] = __builtin_amdgcn_mfma_f32_16x16x32_bf16(Ah, bl[n], acc[m][n], 0, 0, 0);
                    acc[m][n] = __builtin_amdgcn_mfma_f32_16x16x32_bf16(Al, bh[n], acc[m][n], 0, 0, 0);
                }
            }
        };
        #pragma unroll 1
        for (int kk = 0; kk + 2 <= KK; kk += 2) {
            const ushortT* w1 = wqb + (size_t)(kk + 1) * 4096;
            #pragma unroll
            for (int n = 0; n < 4; ++n) {
                bB[n] = *(const bf8_t*)(w1 + boff + n * 128);
                lB[n] = *(const bf8_t*)(w1 + 2048 + boff + n * 128);
            }
            domfma(kk, bA, lA);
            const ushortT* w2 = wqb + (size_t)(kk + 2) * 4096;
            #pragma unroll
            for (int n = 0; n < 4; ++n) {
                bA[n] = *(const bf8_t*)(w2 + boff + n * 128);
                lA[n] = *(const bf8_t*)(w2 + 2048 + boff + n * 128);
            }
            domfma(kk + 1, bB, lB);
        }
        domfma(KK - 1, bA, lA);
        __syncthreads();
    }
    if (NHWCOUT) {
        float* ob0 = out + (size_t)img * outStride;
        #pragma unroll
        for (int m = 0; m < 2; ++m) {
            __syncthreads();
            #pragma unroll
            for (int n = 0; n < 4; ++n)
                #pragma unroll
                for (int j = 0; j < 4; ++j) {
                    float v = acc[m][n][j];
                    if (ACT == 1) v = fmaxf(v, 0.f);
                    else if (ACT == 2) v = 1.f / (1.f + __expf(-fmaxf(v, 0.f)));
                    pool[(wv * 16 + kb * 4 + j) * 68 + n * 16 + lc] = v;
                }
            __syncthreads();
            {
                int pix = t >> 2, q = t & 3;
                int y = y0 + 2 * (pix >> 4) + m;
                int x = x0 + (pix & 15);
                float* pr = ob0 + ((size_t)y * WID + x) * 64 + q * 16;
                const float* src = &pool[pix * 68 + q * 16];
                #pragma unroll
                for (int u = 0; u < 4; ++u)
                    *(float4*)&pr[u * 4] = *(const float4*)&src[u * 4];
            }
        }
    } else {
        // ---- direct float4 NCHW store (no LDS, no barriers) ----
        float* ob0 = out + (size_t)img * outStride + (size_t)(g * 64) * HW;
        #pragma unroll
        for (int m = 0; m < 2; ++m) {
            const int y = y0 + 2 * wv + m;
            #pragma unroll
            for (int n = 0; n < 4; ++n) {
                f4_t v = acc[m][n];
                float4 st;
                #pragma unroll
                for (int j = 0; j < 4; ++j) {
                    float vv = v[j];
                    if (ACT == 1) vv = fmaxf(vv, 0.f);
                    else if (ACT == 2) vv = 1.f / (1.f + __expf(-fmaxf(vv, 0.f)));
                    ((float*)&st)[j] = vv;
                }
                *(float4*)&ob0[(size_t)(n * 16 + lc) * HW + (size_t)y * WID + x0 + kb * 4] = st;
            }
        }
    }
}

// ---------------------------------------------------------------------
__global__ __launch_bounds__(256) void ln_stats(
    const float* __restrict__ x, float* __restrict__ mu, float* __restrict__ rs)
{
    const int p = blockIdx.x * 256 + threadIdx.x;
    const int img = p / HW, pp = p - img * HW;
    const float* b = x + (size_t)img * 64 * HW + pp;
    float row[64];
    #pragma unroll
    for (int c = 0; c < 64; ++c) row[c] = b[(size_t)c * HW];
    float s1 = 0.f;
    #pragma unroll
    for (int c = 0; c < 64; ++c) s1 += row[c];
    float m = s1 * (1.f / 64.f);
    float s2 = 0.f;
    #pragma unroll
    for (int c = 0; c < 64; ++c) { float d = row[c] - m; s2 += d * d; }
    mu[p] = m;
    rs[p] = rsqrtf(s2 * (1.f / 64.f) + 1e-5f);
}

// ---------------------------------------------------------------------
__global__ __launch_bounds__(256) void xb1x1(
    const float* __restrict__ x, const float* __restrict__ xbas,
    const float* __restrict__ xo, const float* __restrict__ b1, const float* __restrict__ b2,
    const float* __restrict__ c7w, const float* __restrict__ c7b,
    const float* __restrict__ c8w, const float* __restrict__ c8b,
    float* __restrict__ xbout)
{
    __shared__ __align__(16) float w7s[128 * 36], w8s[128 * 36];
    const int t = threadIdx.x, oh = blockIdx.y;
    for (int i = t; i < 4096; i += 256) {
        int o = i >> 7, ic = i & 127;
        w7s[ic * 36 + o] = c7w[(size_t)(oh * 32 + o) * 128 + ic];
        w8s[ic * 36 + o] = c8w[(size_t)(oh * 32 + o) * 128 + ic];
    }
    __syncthreads();
    const int p = blockIdx.x * 256 + t;
    const int img = p / HW, pp = p - img * HW;
    const float* b1p = b1 + (size_t)img * 128 * HW + pp;
    const float* b2p = b2 + (size_t)img * 128 * HW + pp;
    const float* xp  = x  + (size_t)img * 64 * HW + pp;
    const float* xbp = xbas + (size_t)img * 64 * HW + pp;
    float a7[32], a8[32];
    {
        const float4* c74 = (const float4*)(c7b + oh * 32);
        const float4* c84 = (const float4*)(c8b + oh * 32);
        #pragma unroll
        for (int j4 = 0; j4 < 8; ++j4) {
            float4 v7 = c74[j4], v8 = c84[j4];
            a7[j4*4+0]=v7.x; a7[j4*4+1]=v7.y; a7[j4*4+2]=v7.z; a7[j4*4+3]=v7.w;
            a8[j4*4+0]=v8.x; a8[j4*4+1]=v8.y; a8[j4*4+2]=v8.z; a8[j4*4+3]=v8.w;
        }
    }
    #pragma unroll 4
    for (int ic = 0; ic < 128; ++ic) {
        float tv = b1p[(size_t)ic * HW] * b2p[(size_t)ic * HW];
        float cv = (ic < 64) ? xp[(size_t)ic * HW] : xbp[(size_t)(ic - 64) * HW];
        const float4* w7r = (const float4*)&w7s[ic * 36];
        const float4* w8r = (const float4*)&w8s[ic * 36];
        #pragma unroll
        for (int j4 = 0; j4 < 8; ++j4) {
            float4 v7 = w7r[j4], v8 = w8r[j4];
            a7[j4*4+0] = fmaf(tv, v7.x, a7[j4*4+0]);
            a7[j4*4+1] = fmaf(tv, v7.y, a7[j4*4+1]);
            a7[j4*4+2] = fmaf(tv, v7.z, a7[j4*4+2]);
            a7[j4*4+3] = fmaf(tv, v7.w, a7[j4*4+3]);
            a8[j4*4+0] = fmaf(cv, v8.x, a8[j4*4+0]);
            a8[j4*4+1] = fmaf(cv, v8.y, a8[j4*4+1]);
            a8[j4*4+2] = fmaf(cv, v8.z, a8[j4*4+2]);
            a8[j4*4+3] = fmaf(cv, v8.w, a8[j4*4+3]);
        }
    }
    const float* xop = xo + (size_t)img * 64 * HW + pp;
    float* orow = xbout + (size_t)p * 64 + oh * 32;
    #pragma unroll
    for (int j4 = 0; j4 < 8; ++j4) {
        float4 st;
        st.x = xop[(size_t)(oh*32 + j4*4+0) * HW] * fmaxf(a7[j4*4+0], 0.f) + fmaxf(a8[j4*4+0], 0.f);
        st.y = xop[(size_t)(oh*32 + j4*4+1) * HW] * fmaxf(a7[j4*4+1], 0.f) + fmaxf(a8[j4*4+1], 0.f);
        st.z = xop[(size_t)(oh*32 + j4*4+2) * HW] * fmaxf(a7[j4*4+2], 0.f) + fmaxf(a8[j4*4+2], 0.f);
        st.w = xop[(size_t)(oh*32 + j4*4+3) * HW] * fmaxf(a7[j4*4+3], 0.f) + fmaxf(a8[j4*4+3], 0.f);
        *(float4*)&orow[j4 * 4] = st;
    }
}

// ---------------------------------------------------------------------
// MFMA window attention, Q-in-registers (round 15, unchanged).
// ---------------------------------------------------------------------
__global__ __launch_bounds__(256) void attn(
    const float* __restrict__ xc, const float* __restrict__ xb,
    const float* __restrict__ qkvw, const float* __restrict__ qkvb,
    const float* __restrict__ corw, const float* __restrict__ corb,
    float* __restrict__ aout)
{
    constexpr int QS = 40;
    constexpr int VS = 212;
    __shared__ __align__(16) ushortT Kth[196 * QS];
    __shared__ __align__(16) ushortT Ktl[196 * QS];
    __shared__ __align__(16) ushortT Vth[16 * VS];
    __shared__ __align__(16) ushortT Vtl[16 * VS];
    __shared__ __align__(16) float CB[208];

    const int t = threadIdx.x;
    const int wdw = blockIdx.x >> 2, h = blockIdx.x & 3;
    const int b = wdw >> 8, wl = wdw & 255;
    const int wy = (wl >> 4) * 14, wx = (wl & 15) * 14;
    const int lane = t & 63, wv = t >> 6;
    const int g = lane >> 4, col = lane & 15;

    bf8_t Wqh[2], Wql[2], Wkh[2], Wkl[2], Wvh[2], Wvl[2];
    float qb[4], kb[4], vb[4];
    {
        #pragma unroll
        for (int ks = 0; ks < 2; ++ks) {
            float xv[8];
            const float* wr = qkvw + (h * 16 + col) * 64 + ks * 32 + g * 8;
            *(float4*)&xv[0] = *(const float4*)wr;
            *(float4*)&xv[4] = *(const float4*)(wr + 4);
            cvt8(xv, Wqh[ks], Wql[ks]);
            wr = qkvw + (64 + h * 16 + col) * 64 + ks * 32 + g * 8;
            *(float4*)&xv[0] = *(const float4*)wr;
            *(float4*)&xv[4] = *(const float4*)(wr + 4);
            cvt8(xv, Wkh[ks], Wkl[ks]);
            wr = qkvw + (128 + h * 16 + col) * 64 + ks * 32 + g * 8;
            *(float4*)&xv[0] = *(const float4*)wr;
            *(float4*)&xv[4] = *(const float4*)(wr + 4);
            cvt8(xv, Wvh[ks], Wvl[ks]);
        }
        float4 q4 = *(const float4*)(qkvb + h * 16 + g * 4);
        float4 k4 = *(const float4*)(qkvb + 64 + h * 16 + g * 4);
        float4 v4 = *(const float4*)(qkvb + 128 + h * 16 + g * 4);
        qb[0]=q4.x; qb[1]=q4.y; qb[2]=q4.z; qb[3]=q4.w;
        kb[0]=k4.x; kb[1]=k4.y; kb[2]=k4.z; kb[3]=k4.w;
        vb[0]=v4.x; vb[1]=v4.y; vb[2]=v4.z; vb[3]=v4.w;
    }

    if (t < 208) CB[t] = (t < 196) ? corb[t] : 0.f;
    if (t < 196) {
        unsigned* khr = (unsigned*)&Kth[t * QS];
        unsigned* klr = (unsigned*)&Ktl[t * QS];
        float xw[16];
        const float4* cw4 = (const float4*)(corw + t * 16);
        #pragma unroll
        for (int j = 0; j < 4; ++j) *(float4*)&xw[j * 4] = cw4[j];
        #pragma unroll
        for (int i = 0; i < 8; ++i) {
            ushortT ah = f2bf(xw[2*i]), bh = f2bf(xw[2*i+1]);
            ushortT al = f2bf(xw[2*i] - bf2f(ah)), bl = f2bf(xw[2*i+1] - bf2f(bh));
            khr[8 + i] = (unsigned)ah | ((unsigned)bh << 16);
            klr[8 + i] = (unsigned)al | ((unsigned)bl << 16);
        }
    }

    auto phaseB = [&](int mt) -> f4_t {
        const int row = 16 * mt + col;
        const int pix = (row > 195) ? 195 : row;
        const int rr = pix / 14, cc = pix - (pix / 14) * 14;
        const float* xr = xc + (size_t)((b * 224 + wy + rr) * 224 + wx + cc) * 64;
        f4_t dq = (f4_t){0.f, 0.f, 0.f, 0.f};
        f4_t dk = (f4_t){0.f, 0.f, 0.f, 0.f};
        f4_t dv = (f4_t){0.f, 0.f, 0.f, 0.f};
        #pragma unroll
        for (int ks = 0; ks < 2; ++ks) {
            float xv[8];
            *(float4*)&xv[0] = *(const float4*)(xr + ks * 32 + g * 8);
            *(float4*)&xv[4] = *(const float4*)(xr + ks * 32 + g * 8 + 4);
            bf8_t Xh, Xl;
            cvt8(xv, Xh, Xl);
            dq = __builtin_amdgcn_mfma_f32_16x16x32_bf16(Wqh[ks], Xh, dq, 0, 0, 0);
            dq = __builtin_amdgcn_mfma_f32_16x16x32_bf16(Wqh[ks], Xl, dq, 0, 0, 0);
            dq = __builtin_amdgcn_mfma_f32_16x16x32_bf16(Wql[ks], Xh, dq, 0, 0, 0);
            dk = __builtin_amdgcn_mfma_f32_16x16x32_bf16(Wkh[ks], Xh, dk, 0, 0, 0);
            dk = __builtin_amdgcn_mfma_f32_16x16x32_bf16(Wkh[ks], Xl, dk, 0, 0, 0);
            dk = __builtin_amdgcn_mfma_f32_16x16x32_bf16(Wkl[ks], Xh, dk, 0, 0, 0);
            dv = __builtin_amdgcn_mfma_f32_16x16x32_bf16(Wvh[ks], Xh, dv, 0, 0, 0);
            dv = __builtin_amdgcn_mfma_f32_16x16x32_bf16(Wvh[ks], Xl, dv, 0, 0, 0);
            dv = __builtin_amdgcn_mfma_f32_16x16x32_bf16(Wvl[ks], Xh, dv, 0, 0, 0);
        }
        #pragma unroll
        for (int j = 0; j < 4; ++j) {
            float v = dv[j] + vb[j];
            ushortT hi = f2bf(v);
            Vth[(g * 4 + j) * VS + row] = hi;
            Vtl[(g * 4 + j) * VS + row] = f2bf(v - bf2f(hi));
        }
        if (row < 196) {
            unsigned h0, h1, l0, l1;
            {
                float a = dk[0] + kb[0], bb = dk[1] + kb[1];
                ushortT ah = f2bf(a), bh = f2bf(bb);
                h0 = (unsigned)ah | ((unsigned)bh << 16);
                l0 = (unsigned)f2bf(a - bf2f(ah)) | ((unsigned)f2bf(bb - bf2f(bh)) << 16);
            }
            {
                float a = dk[2] + kb[2], bb = dk[3] + kb[3];
                ushortT ah = f2bf(a), bh = f2bf(bb);
                h1 = (unsigned)ah | ((unsigned)bh << 16);
                l1 = (unsigned)f2bf(a - bf2f(ah)) | ((unsigned)f2bf(bb - bf2f(bh)) << 16);
            }
            uint2 u;
            u.x = h0; u.y = h1; *(uint2*)&Kth[row * QS + g * 4] = u;
            u.x = l0; u.y = l1; *(uint2*)&Ktl[row * QS + g * 4] = u;
        }
        return (f4_t){(dq[0] + qb[0]) * 0.25f, (dq[1] + qb[1]) * 0.25f,
                      (dq[2] + qb[2]) * 0.25f, (dq[3] + qb[3]) * 0.25f};
    };

    f4_t dqs0 = phaseB(wv);
    f4_t dqs1 = phaseB(wv + 4);
    f4_t dqs2 = phaseB(wv + 8);
    f4_t dqs3 = (f4_t){0.f, 0.f, 0.f, 0.f};
    if (wv == 0) dqs3 = phaseB(12);
    __syncthreads();

    auto phaseC = [&](f4_t dqv, int qt) {
        const int row = 16 * qt + col;
        const int pixq = (row > 195) ? 195 : row;
        float q8[8];
        const int sl0 = ((2 * g) & 3) * 16 + col;
        const int sl1 = ((2 * g + 1) & 3) * 16 + col;
        q8[0] = __shfl(dqv[0], sl0); q8[1] = __shfl(dqv[1], sl0);
        q8[2] = __shfl(dqv[2], sl0); q8[3] = __shfl(dqv[3], sl0);
        q8[4] = __shfl(dqv[0], sl1); q8[5] = __shfl(dqv[1], sl1);
        q8[6] = __shfl(dqv[2], sl1); q8[7] = __shfl(dqv[3], sl1);
        if (g >= 2) {
            const int rr = pixq / 14, cc = pixq - (pixq / 14) * 14;
            const float* xr = xb + (size_t)((b * 224 + wy + rr) * 224 + wx + cc) * 64
                            + h * 16 + (g & 1) * 8;
            *(float4*)&q8[0] = *(const float4*)xr;
            *(float4*)&q8[4] = *(const float4*)(xr + 4);
        }
        bf8_t Bhf, Blf;
        cvt8(q8, Bhf, Blf);
        f4_t s[13];
        __builtin_amdgcn_s_setprio(1);
        #pragma unroll
        for (int kt = 0; kt < 13; ++kt) {
            const int krow = (16 * kt + col > 195) ? 195 : (16 * kt + col);
            const bf8_t Ahf = *(const bf8_t*)&Kth[krow * QS + g * 8];
            const bf8_t Alf = *(const bf8_t*)&Ktl[krow * QS + g * 8];
            f4_t a = (f4_t){0.f, 0.f, 0.f, 0.f};
            a = __builtin_amdgcn_mfma_f32_16x16x32_bf16(Ahf, Bhf, a, 0, 0, 0);
            a = __builtin_amdgcn_mfma_f32_16x16x32_bf16(Ahf, Blf, a, 0, 0, 0);
            a = __builtin_amdgcn_mfma_f32_16x16x32_bf16(Alf, Bhf, a, 0, 0, 0);
            const f4_t cb4 = *(const f4_t*)&CB[16 * kt + g * 4];
            s[kt] = a + cb4;
        }
        __builtin_amdgcn_s_setprio(0);
        if (g > 0) { s[12][0] = -3e38f; s[12][1] = -3e38f; s[12][2] = -3e38f; s[12][3] = -3e38f; }
        float mrow = -3e38f;
        #pragma unroll
        for (int kt = 0; kt < 13; ++kt)
            #pragma unroll
            for (int j = 0; j < 4; ++j) mrow = fmaxf(mrow, s[kt][j]);
        mrow = fmaxf(mrow, __shfl_xor(mrow, 16));
        mrow = fmaxf(mrow, __shfl_xor(mrow, 32));
        float lsum = 0.f;
        bf4_t ph[13], pl[13];
        #pragma unroll
        for (int kt = 0; kt < 13; ++kt) {
            #pragma unroll
            for (int j = 0; j < 4; ++j) {
                float p = __expf(s[kt][j] - mrow);
                lsum += p;
                ushortT hi = f2bf(p);
                ph[kt][j] = (short)hi;
                pl[kt][j] = (short)f2bf(p - bf2f(hi));
            }
        }
        lsum += __shfl_xor(lsum, 16);
        lsum += __shfl_xor(lsum, 32);
        f4_t o = (f4_t){0.f, 0.f, 0.f, 0.f};
        __builtin_amdgcn_s_setprio(1);
        #pragma unroll
        for (int kt = 0; kt < 13; ++kt) {
            const bf4_t vh = *(const bf4_t*)&Vth[col * VS + 16 * kt + g * 4];
            const bf4_t vl = *(const bf4_t*)&Vtl[col * VS + 16 * kt + g * 4];
            o = __builtin_amdgcn_mfma_f32_16x16x16bf16_1k(vh, ph[kt], o, 0, 0, 0);
            o = __builtin_amdgcn_mfma_f32_16x16x16bf16_1k(vl, ph[kt], o, 0, 0, 0);
            o = __builtin_amdgcn_mfma_f32_16x16x16bf16_1k(vh, pl[kt], o, 0, 0, 0);
        }
        __builtin_amdgcn_s_setprio(0);
        const int pix = 16 * qt + col;
        if (pix < 196) {
            const float inv = 1.f / lsum;
            const int rr = pix / 14, cc = pix % 14;
            const size_t pixIdx = (size_t)((b * 224 + wy + rr) * 224 + wx + cc);
            float4 st = { o[0] * inv, o[1] * inv, o[2] * inv, o[3] * inv };
            *(float4*)&aout[pixIdx * 64 + h * 16 + g * 4] = st;
        }
    };

    phaseC(dqs0, wv);
    phaseC(dqs1, wv + 4);
    phaseC(dqs2, wv + 8);
    if (wv == 0) phaseC(dqs3, 12);
}

// ---------------------------------------------------------------------
// MFMA proj+LN+MLP (round 16, unchanged).
// ---------------------------------------------------------------------
__global__ __launch_bounds__(256) void mlpmf(
    const float* __restrict__ aout, const ushortT* __restrict__ pk,
    const float* __restrict__ pbias,
    const float* __restrict__ lng, const float* __restrict__ lnb,
    const float* __restrict__ fc1b, const float* __restrict__ fc2b,
    float* __restrict__ out)
{
    const int t = threadIdx.x, lane = t & 63, wv = t >> 6;
    const int gq = lane >> 4, col = lane & 15;
    const int p0 = (blockIdx.x * 4 + wv) * 16;
    const ushortT* pk1 = pk;
    const ushortT* pk2 = pk + 8192;
    const ushortT* pk3 = pk + 24576;

    f4_t S[4];
    #pragma unroll
    for (int n = 0; n < 4; ++n) {
        float4 b4 = *(const float4*)(pbias + n * 16 + gq * 4);
        S[n] = (f4_t){b4.x, b4.y, b4.z, b4.w};
    }
    const float* xr = aout + (size_t)(p0 + col) * 64;
    #pragma unroll
    for (int ks = 0; ks < 2; ++ks) {
        float xv[8];
        *(float4*)&xv[0] = *(const float4*)(xr + ks * 32 + gq * 8);
        *(float4*)&xv[4] = *(const float4*)(xr + ks * 32 + gq * 8 + 4);
        bf8_t Xh, Xl;
        cvt8(xv, Xh, Xl);
        #pragma unroll
        for (int n = 0; n < 4; ++n) {
            const ushortT* a = pk1 + (size_t)(n * 2 + ks) * 1024 + lane * 8;
            bf8_t Ah = *(const bf8_t*)a;
            bf8_t Al = *(const bf8_t*)(a + 512);
            S[n] = __builtin_amdgcn_mfma_f32_16x16x32_bf16(Ah, Xh, S[n], 0, 0, 0);
            S[n] = __builtin_amdgcn_mfma_f32_16x16x32_bf16(Ah, Xl, S[n], 0, 0, 0);
            S[n] = __builtin_amdgcn_mfma_f32_16x16x32_bf16(Al, Xh, S[n], 0, 0, 0);
        }
    }
    float sum = 0.f;
    #pragma unroll
    for (int n = 0; n < 4; ++n)
        #pragma unroll
        for (int j = 0; j < 4; ++j) sum += S[n][j];
    sum += __shfl_xor(sum, 16);
    sum += __shfl_xor(sum, 32);
    float mean = sum * (1.f / 64.f);
    float var = 0.f;
    #pragma unroll
    for (int n = 0; n < 4; ++n)
        #pragma unroll
        for (int j = 0; j < 4; ++j) { float d = S[n][j] - mean; var += d * d; }
    var += __shfl_xor(var, 16);
    var += __shfl_xor(var, 32);
    float rstd = rsqrtf(var * (1.f / 64.f) + 1e-5f);
    bf4_t Nh[4], Nl[4];
    #pragma unroll
    for (int n = 0; n < 4; ++n) {
        float4 g4 = *(const float4*)(lng + n * 16 + gq * 4);
        float4 b4 = *(const float4*)(lnb + n * 16 + gq * 4);
        float nv0 = (S[n][0] - mean) * rstd * g4.x + b4.x;
        float nv1 = (S[n][1] - mean) * rstd * g4.y + b4.y;
        float nv2 = (S[n][2] - mean) * rstd * g4.z + b4.z;
        float nv3 = (S[n][3] - mean) * rstd * g4.w + b4.w;
        ushortT h0 = f2bf(nv0), h1 = f2bf(nv1), h2 = f2bf(nv2), h3 = f2bf(nv3);
        Nh[n][0] = (short)h0; Nh[n][1] = (short)h1; Nh[n][2] = (short)h2; Nh[n][3] = (short)h3;
        Nl[n][0] = (short)f2bf(nv0 - bf2f(h0));
        Nl[n][1] = (short)f2bf(nv1 - bf2f(h1));
        Nl[n][2] = (short)f2bf(nv2 - bf2f(h2));
        Nl[n][3] = (short)f2bf(nv3 - bf2f(h3));
    }
    bf4_t Gh[8], Gl[8];
    #pragma unroll
    for (int o = 0; o < 8; ++o) {
        float4 b4 = *(const float4*)(fc1b + o * 16 + gq * 4);
        f4_t hacc = (f4_t){b4.x, b4.y, b4.z, b4.w};
        #pragma unroll
        for (int n = 0; n < 4; ++n) {
            const ushortT* a = pk2 + (size_t)(o * 4 + n) * 512 + lane * 4;
            bf4_t Ah = *(const bf4_t*)a;
            bf4_t Al = *(const bf4_t*)(a + 256);
            hacc = __builtin_amdgcn_mfma_f32_16x16x16bf16_1k(Ah, Nh[n], hacc, 0, 0, 0);
            hacc = __builtin_amdgcn_mfma_f32_16x16x16bf16_1k(Ah, Nl[n], hacc, 0, 0, 0);
            hacc = __builtin_amdgcn_mfma_f32_16x16x16bf16_1k(Al, Nh[n], hacc, 0, 0, 0);
        }
        #pragma unroll
        for (int j = 0; j < 4; ++j) {
            float hv = hacc[j];
            float gl = 0.5f * hv * (1.f + erff(hv * 0.70710678118f));
            ushortT hi = f2bf(gl);
            Gh[o][j] = (short)hi;
            Gl[o][j] = (short)f2bf(gl - bf2f(hi));
        }
    }
    const int img = p0 / HW, pp = p0 - img * HW;
    float* ob = out + (size_t)img * 64 * HW + pp + col;
    #pragma unroll
    for (int o2 = 0; o2 < 4; ++o2) {
        float4 b4 = *(const float4*)(fc2b + o2 * 16 + gq * 4);
        f4_t oacc = (f4_t){b4.x, b4.y, b4.z, b4.w};
        #pragma unroll
        for (int k2 = 0; k2 < 8; ++k2) {
            const ushortT* a = pk3 + (size_t)(o2 * 8 + k2) * 512 + lane * 4;
            bf4_t Ah = *(const bf4_t*)a;
            bf4_t Al = *(const bf4_t*)(a + 256);
            oacc = __builtin_amdgcn_mfma_f32_16x16x16bf16_1k(Ah, Gh[k2], oacc, 0, 0, 0);
            oacc = __builtin_amdgcn_mfma_f32_16x16x16bf16_1k(Ah, Gl[k2], oacc, 0, 0, 0);
            oacc = __builtin_amdgcn_mfma_f32_16x16x16bf16_1k(Al, Gh[k2], oacc, 0, 0, 0);
        }
        #pragma unroll
        for (int j = 0; j < 4; ++j) {
            int och = o2 * 16 + gq * 4 + j;
            ob[(size_t)och * HW] = S[o2][j] + oacc[j];
        }
    }
}

// ---------------------------------------------------------------------
extern "C" void kernel_launch(void* const* d_in, const int* in_sizes, int n_in,
                              void* d_out, int out_size, void* d_ws, size_t ws_size,
                              hipStream_t stream)
{
    (void)in_sizes; (void)n_in; (void)out_size;
    const float* x      = (const float*)d_in[0];
    const float* xbasic = (const float*)d_in[1];
    const float* c1w  = (const float*)d_in[2];  const float* c1b  = (const float*)d_in[3];
    const float* c2w  = (const float*)d_in[4];  const float* c2b  = (const float*)d_in[5];
    const float* c3w  = (const float*)d_in[6];  const float* c3b  = (const float*)d_in[7];
    const float* c4w  = (const float*)d_in[8];  const float* c4b  = (const float*)d_in[9];
    const float* c5w  = (const float*)d_in[10]; const float* c5b  = (const float*)d_in[11];
    const float* c6w  = (const float*)d_in[12]; const float* c6b  = (const float*)d_in[13];
    const float* c7w  = (const float*)d_in[14]; const float* c7b  = (const float*)d_in[15];
    const float* c8w  = (const float*)d_in[16]; const float* c8b  = (const float*)d_in[17];
    const float* qk1w = (const float*)d_in[18]; const float* qk1b = (const float*)d_in[19];
    const float* n1g  = (const float*)d_in[20]; const float* n1b  = (const float*)d_in[21];
    const float* qkvw = (const float*)d_in[22]; const float* qkvb = (const float*)d_in[23];
    const float* corw = (const float*)d_in[24]; const float* corb = (const float*)d_in[25];
    const float* prjw = (const float*)d_in[26]; const float* prjb = (const float*)d_in[27];
    const float* n2g  = (const float*)d_in[28]; const float* n2b  = (const float*)d_in[29];
    const float* f1w  = (const float*)d_in[30]; const float* f1b  = (const float*)d_in[31];
    const float* f2w  = (const float*)d_in[32]; const float* f2b  = (const float*)d_in[33];

    float* ws = (float*)d_ws;
    const size_t SCR0 = 26836992ull;
    const size_t need4 = (SCR0 + 4ull * 19267584ull) * 4ull;  // 415.6 MB
    const size_t need2 = (SCR0 + 2ull * 19267584ull) * 4ull;  // 261.5 MB
    const int CS = (ws_size >= need4) ? 4 : (ws_size >= need2) ? 2 : 1;
    const int nch = 4 / CS;

    float* XC = ws;
    float* XB = ws + 12845056;
    float* MU = ws + 25690112;
    float* RS = ws + 25890816;
    ushortT* WP = (ushortT*)(ws + 26091520);
    float* A  = ws + SCR0;
    float* XO = A + (size_t)CS * 9633792;
    float* B1 = XO + (size_t)CS * 3211264;
    float* B2 = A;          // alias (A dead after c4)
    float* AOUT = A;        // alias (conv scratch dead at attn time)
    ushortT* WQ1 = (ushortT*)B1;  // transient: qkv1 packed weights (73728 u16)
    ushortT* PM  = (ushortT*)MU;  // mlp packed weights (40960 u16; MU dead after qkv1)

    const size_t o1 = 0, o2 = 73728, o3 = 278528, o4 = 679936, o5 = 901120, o6 = 1196032;

    ln_stats<<<784, 256, 0, stream>>>(x, MU, RS);

    // ---- pre-pack conv weights ----
    {
        auto PK = [&](const float* w, ushortT* dst, int K, int IC, int OC) {
            int tot = OC * IC * K * K;
            packw<<<(tot + 255) / 256, 256, 0, stream>>>(w, dst, K, IC, OC, tot);
        };
        PK(qk1w, WQ1, 3, 64, 64);
        PK(c1w, WP + o1, 3, 64, 64);
        PK(c2w, WP + o2, 5, 64, 64);
        PK(c3w, WP + o3, 7, 64, 64);
        PK(c4w, WP + o4, 3, 192, 64);
        PK(c5w, WP + o5, 3, 128, 128);
        PK(c6w, WP + o6, 3, 128, 128);
    }

    // ---- qkv1: LN-fused MFMA conv, NHWC out (consumes MU/RS) ----
    mfconv<3, 64, 64, 0, false, true, true><<<dim3(14, 28, 4), 256, 0, stream>>>(
        x, nullptr, WQ1, qk1b, MU, RS, n1g, n1b, XC, 64 * HW, HW * 64);

    // ---- pack MLP weights into MU (dead now) ----
    packa32<<<16, 256, 0, stream>>>(prjw, PM, 64, 4096);
    packa16<<<32, 256, 0, stream>>>(f1w, PM + 8192, 64, 8192);
    packa16<<<32, 256, 0, stream>>>(f2w, PM + 24576, 128, 8192);

    for (int ch = 0; ch < nch; ++ch) {
        const float* xi  = x      + (size_t)ch * CS * 64 * HW;
        const float* xbi = xbasic + (size_t)ch * CS * 64 * HW;
        mfconv3<<<dim3(14, 28, CS), 256, 0, stream>>>(
            xi, WP + o1, WP + o2, WP + o3, c1b, c2b, c3b, A, 64 * HW, 192 * HW);
        mfconv<3, 192, 64, 1, false, false, false><<<dim3(14, 28, CS), 256, 0, stream>>>(
            A, nullptr, WP + o4, c4b, nullptr, nullptr, nullptr, nullptr, XO, 192 * HW, 64 * HW);
        mfconv<3, 128, 128, 1, true, false, false><<<dim3(14, 28, CS * 2), 256, 0, stream>>>(
            xi, xbi, WP + o5, c5b, nullptr, nullptr, nullptr, nullptr, B1, 64 * HW, 128 * HW);
        mfconv<3, 128, 128, 2, false, false, false><<<dim3(14, 28, CS * 2), 256, 0, stream>>>(
            B1, nullptr, WP + o6, c6b, nullptr, nullptr, nullptr, nullptr, B2, 128 * HW, 128 * HW);
        xb1x1<<<dim3(CS * 196, 2), 256, 0, stream>>>(
            xi, xbi, XO, B1, B2, c7w, c7b, c8w, c8b, XB + (size_t)ch * CS * HW * 64);
    }

    attn<<<4096, 256, 0, stream>>>(XC, XB, qkvw, qkvb, corw, corb, AOUT);
    mlpmf<<<3136, 256, 0, stream>>>(AOUT, PM, prjb, n2g, n2b, f1b, f2b,
                                    (float*)d_out);
}

// Round 19
// 1613.828 us; speedup vs baseline: 1.7206x; 1.7206x over previous
//
#include <hip/hip_runtime.h>
#include <hip/hip_bf16.h>
#include <math.h>

// =====================================================================
// SwinTransformerBlock forward, round 25: round-22 base (best, 1648us)
//   + paired-channel u32 LDS staging writes. Round 24's full T14
//   prefetch regressed (VGPR 104->164, occupancy halved, spills ->
//   FETCH +10MB): mfconv3's 96-reg acc + 64-reg B ping-pong leaves no
//   headroom for 40 prefetch regs. This round keeps the r22 structure
//   and halves staging LDS-write instructions instead: each thread
//   handles channels (2c, 2c+1) -- adjacent u16 slots in the [px][icn]
//   layout (ICP=40, 4B-aligned) -- writing one u32 for the hi pair and
//   one for the lo pair. Addr/predicate VALU per element also halves;
//   global loads stay coalesced; +8 VGPR only. Arithmetic identical.
// Workspace: as round 16.
// =====================================================================

#define HW  50176
#define WID 224

typedef unsigned short ushortT;
typedef __attribute__((ext_vector_type(8))) short bf8_t;
typedef __attribute__((ext_vector_type(4))) short bf4_t;
typedef __attribute__((ext_vector_type(4))) float f4_t;

__device__ __forceinline__ ushortT f2bf(float v) {
    __hip_bfloat16 h = __float2bfloat16(v);   // HW cvt, round-to-nearest-even
    ushortT u; __builtin_memcpy(&u, &h, 2); return u;
}
__device__ __forceinline__ float bf2f(ushortT h) {
    union { float f; unsigned int u; } c; c.u = ((unsigned int)h) << 16;
    return c.f;
}
__device__ __forceinline__ void cvt8(const float* xv, bf8_t& hh, bf8_t& ll) {
    #pragma unroll
    for (int i = 0; i < 8; ++i) {
        ushortT hi = f2bf(xv[i]);
        hh[i] = (short)hi;
        ll[i] = (short)f2bf(xv[i] - bf2f(hi));
    }
}

// ---------------------------------------------------------------------
// Pre-pack conv weights (OIHW f32) into B-fragment order bf16 hi/lo.
// ---------------------------------------------------------------------
__global__ __launch_bounds__(256) void packw(
    const float* __restrict__ w, ushortT* __restrict__ dst,
    int K, int IC, int OC, int total)
{
    int e = blockIdx.x * 256 + threadIdx.x;
    if (e >= total) return;
    int KK = K * K;
    int kk = e % KK; int rem = e / KK;
    int ic = rem % IC; int oc = rem / IC;
    float v = w[e];
    ushortT hi = f2bf(v);
    ushortT lo = f2bf(v - bf2f(hi));
    int g = oc >> 6, oc64 = oc & 63;
    int ic32 = ic >> 5, icin = ic & 31, kb = icin >> 3, ii = icin & 7;
    int nch = KK * (IC / 32);
    int chunk = ic32 * KK + kk;
    size_t base = ((size_t)(g * nch + chunk)) * 4096;
    dst[base + (kb * 64 + oc64) * 8 + ii] = hi;
    dst[base + 2048 + (kb * 64 + oc64) * 8 + ii] = lo;
}

// ---------------------------------------------------------------------
// Pack a [OC][K] f32 matrix into 16x16x32 A-fragment order (hi/lo).
// ---------------------------------------------------------------------
__global__ __launch_bounds__(256) void packa32(
    const float* __restrict__ w, ushortT* __restrict__ dst, int K, int total)
{
    int e = blockIdx.x * 256 + threadIdx.x;
    if (e >= total) return;
    int f = e >> 9, r = e & 511, ln = r >> 3, i = r & 7;
    int nk = K >> 5;
    int o = f / nk, ks = f % nk;
    int c = ln & 15, gg = ln >> 4;
    float v = w[(size_t)(o * 16 + c) * K + ks * 32 + gg * 8 + i];
    ushortT hi = f2bf(v);
    dst[(size_t)f * 1024 + ln * 8 + i] = hi;
    dst[(size_t)f * 1024 + 512 + ln * 8 + i] = f2bf(v - bf2f(hi));
}

// ---------------------------------------------------------------------
// Pack a [OC][K] f32 matrix into 16x16x16 A-fragment order (hi/lo).
// ---------------------------------------------------------------------
__global__ __launch_bounds__(256) void packa16(
    const float* __restrict__ w, ushortT* __restrict__ dst, int K, int total)
{
    int e = blockIdx.x * 256 + threadIdx.x;
    if (e >= total) return;
    int f = e >> 8, r = e & 255, ln = r >> 2, i = r & 3;
    int nk = K >> 4;
    int o = f / nk, n = f % nk;
    int c = ln & 15, gg = ln >> 4;
    float v = w[(size_t)(o * 16 + c) * K + n * 16 + gg * 4 + i];
    ushortT hi = f2bf(v);
    dst[(size_t)f * 512 + ln * 4 + i] = hi;
    dst[(size_t)f * 512 + 256 + ln * 4 + i] = f2bf(v - bf2f(hi));
}

// ---------------------------------------------------------------------
// One conv's MFMA pass over the shared staged tile (origin -3, TWd=22).
// Copy-free B ping-pong: pairs of kk with two named register sets.
// ---------------------------------------------------------------------
template<int K>
__device__ __forceinline__ void convpass(
    const ushortT* __restrict__ wq, const ushortT* __restrict__ sm,
    int wv, int lc, int kb, f4_t (&ac)[2][4])
{
    constexpr int off = 3 - K / 2;
    constexpr int INSH = 14 * 22 * 40;
    constexpr int KK = K * K;              // odd: 9 / 25 / 49
    const int boff = (kb * 64 + lc) * 8;

    bf8_t bA[4], lA[4], bB[4], lB[4];
    #pragma unroll
    for (int n = 0; n < 4; ++n) {
        bA[n] = *(const bf8_t*)(wq + boff + n * 128);
        lA[n] = *(const bf8_t*)(wq + 2048 + boff + n * 128);
    }
    auto domfma = [&](int kk, bf8_t (&bh)[4], bf8_t (&bl)[4]) {
        const int ky = kk / K, kx = kk % K;
        #pragma unroll
        for (int m = 0; m < 2; ++m) {
            const int row = 2 * wv + m + ky + off;
            const int col = lc + kx + off;
            const ushortT* ab = sm + (row * 22 + col) * 40 + kb * 8;
            bf8_t Ah = *(const bf8_t*)ab;
            bf8_t Al = *(const bf8_t*)(ab + INSH);
            #pragma unroll
            for (int n = 0; n < 4; ++n) {
                ac[m][n] = __builtin_amdgcn_mfma_f32_16x16x32_bf16(Ah, bh[n], ac[m][n], 0, 0, 0);
                ac[m][n] = __builtin_amdgcn_mfma_f32_16x16x32_bf16(Ah, bl[n], ac[m][n], 0, 0, 0);
                ac[m][n] = __builtin_amdgcn_mfma_f32_16x16x32_bf16(Al, bh[n], ac[m][n], 0, 0, 0);
            }
        }
    };
    #pragma unroll 1
    for (int kk = 0; kk + 2 <= KK; kk += 2) {
        const ushortT* w1 = wq + (size_t)(kk + 1) * 4096;
        #pragma unroll
        for (int n = 0; n < 4; ++n) {
            bB[n] = *(const bf8_t*)(w1 + boff + n * 128);
            lB[n] = *(const bf8_t*)(w1 + 2048 + boff + n * 128);
        }
        domfma(kk, bA, lA);
        const ushortT* w2 = wq + (size_t)(kk + 2) * 4096;   // kk+2 <= KK-1
        #pragma unroll
        for (int n = 0; n < 4; ++n) {
            bA[n] = *(const bf8_t*)(w2 + boff + n * 128);
            lA[n] = *(const bf8_t*)(w2 + 2048 + boff + n * 128);
        }
        domfma(kk + 1, bB, lB);
    }
    domfma(KK - 1, bA, lA);
}

// ---------------------------------------------------------------------
// Fused c1(3x3)+c2(5x5)+c3(7x7) conv, IC=64, OC=64 each, relu, NCHW out.
// Grid: (14, 28, CS). Block 256 = 4 waves. Direct float4 epilogue.
// Staging: paired-channel u32 LDS writes.
// ---------------------------------------------------------------------
__global__ __launch_bounds__(256, 4) void mfconv3(
    const float* __restrict__ in,
    const ushortT* __restrict__ w1p, const ushortT* __restrict__ w2p,
    const ushortT* __restrict__ w3p,
    const float* __restrict__ b1, const float* __restrict__ b2,
    const float* __restrict__ b3,
    float* __restrict__ out, int inStride, int outStride)
{
    constexpr int TWd = 22, THd = 14, ICP = 40;
    constexpr int PX = THd * TWd;              // 308
    constexpr int INSH = PX * ICP;             // 12320
    constexpr int EP = PX * 16;                // 4928 channel-pairs
    __shared__ __align__(16) ushortT smem_u[2 * INSH];

    const int t = threadIdx.x, lane = t & 63, wv = t >> 6;
    const int lc = lane & 15, kb = lane >> 4;
    const int img = blockIdx.z;
    const int x0 = blockIdx.x * 16, y0 = blockIdx.y * 8;
    const float* inb = in + (size_t)img * inStride;

    f4_t acc1[2][4], acc2[2][4], acc3[2][4];
    {
        #pragma unroll
        for (int n = 0; n < 4; ++n) {
            float z1 = b1[n * 16 + lc], z2 = b2[n * 16 + lc], z3 = b3[n * 16 + lc];
            #pragma unroll
            for (int m = 0; m < 2; ++m) {
                acc1[m][n] = (f4_t){z1, z1, z1, z1};
                acc2[m][n] = (f4_t){z2, z2, z2, z2};
                acc3[m][n] = (f4_t){z3, z3, z3, z3};
            }
        }
    }

    #pragma unroll 1
    for (int ic32 = 0; ic32 < 2; ++ic32) {
        __syncthreads();
        // ---- stage K=7-halo chunk: 8-deep loads, paired u32 writes ----
        #pragma unroll 1
        for (int jb = 0; jb < EP; jb += 2048) {
            float v0[8], v1[8];
            #pragma unroll
            for (int u = 0; u < 8; ++u) {
                int j = jb + u * 256 + t;
                v0[u] = 0.f; v1[u] = 0.f;
                if (j < EP) {
                    int ic2 = j / PX;
                    int px  = j - ic2 * PX;
                    int ty = px / TWd, tx = px % TWd;
                    int gy = y0 + ty - 3, gx = x0 + tx - 3;
                    if (gy >= 0 && gy < WID && gx >= 0 && gx < WID) {
                        const float* s = inb + (size_t)(ic32 * 32 + 2 * ic2) * HW
                                       + gy * WID + gx;
                        v0[u] = s[0];
                        v1[u] = s[HW];
                    }
                }
            }
            #pragma unroll
            for (int u = 0; u < 8; ++u) {
                int j = jb + u * 256 + t;
                if (j < EP) {
                    int ic2 = j / PX;
                    int px  = j - ic2 * PX;
                    ushortT h0 = f2bf(v0[u]), h1 = f2bf(v1[u]);
                    ushortT l0 = f2bf(v0[u] - bf2f(h0));
                    ushortT l1 = f2bf(v1[u] - bf2f(h1));
                    *(unsigned*)&smem_u[px * ICP + 2 * ic2] =
                        (unsigned)h0 | ((unsigned)h1 << 16);
                    *(unsigned*)&smem_u[INSH + px * ICP + 2 * ic2] =
                        (unsigned)l0 | ((unsigned)l1 << 16);
                }
            }
        }
        __syncthreads();
        convpass<3>(w1p + (size_t)(ic32 *  9) * 4096, smem_u, wv, lc, kb, acc1);
        convpass<5>(w2p + (size_t)(ic32 * 25) * 4096, smem_u, wv, lc, kb, acc2);
        convpass<7>(w3p + (size_t)(ic32 * 49) * 4096, smem_u, wv, lc, kb, acc3);
    }

    // ---- epilogue: relu + DIRECT float4 NCHW store (no LDS, no bar) ----
    // D layout: oc = n*16+lc, px(x) = kb*4+j (j contiguous), y = y0+2wv+m.
    #pragma unroll
    for (int c = 0; c < 3; ++c) {
        float* ob0 = out + (size_t)img * outStride + (size_t)(c * 64) * HW;
        #pragma unroll
        for (int m = 0; m < 2; ++m) {
            const int y = y0 + 2 * wv + m;
            #pragma unroll
            for (int n = 0; n < 4; ++n) {
                f4_t v = (c == 0) ? acc1[m][n] : (c == 1) ? acc2[m][n] : acc3[m][n];
                float4 st = { fmaxf(v[0], 0.f), fmaxf(v[1], 0.f),
                              fmaxf(v[2], 0.f), fmaxf(v[3], 0.f) };
                *(float4*)&ob0[(size_t)(n * 16 + lc) * HW + (size_t)y * WID + x0 + kb * 4] = st;
            }
        }
    }
}

// ---------------------------------------------------------------------
// MFMA conv. Template: K, IC, OC, ACT(1 relu, 2 sigmoid(relu)), CAT,
// LNRM, NHWCOUT. Grid: (14, 28, CS*OC/64). Block 256 = 4 waves.
// Copy-free B ping-pong kk loop; paired-channel u32 staging writes.
// ---------------------------------------------------------------------
template<int K, int IC, int OC, int ACT, bool CAT, bool LNRM, bool NHWCOUT>
__global__ __launch_bounds__(256, 4) void mfconv(
    const float* __restrict__ in, const float* __restrict__ in2,
    const ushortT* __restrict__ wpk, const float* __restrict__ bias,
    const float* __restrict__ mu, const float* __restrict__ rs,
    const float* __restrict__ lng, const float* __restrict__ lnb,
    float* __restrict__ out, int inStride, int outStride)
{
    constexpr int P = K / 2, TWd = 16 + K - 1, THd = 8 + K - 1, ICP = 40;
    constexpr int OCG = OC / 64, KK = K * K, NCH = KK * (IC / 32);
    constexpr int PX = THd * TWd;
    constexpr int INSH = PX * ICP;
    constexpr int EP = PX * 16;
    constexpr int SMU = (2 * INSH > 10240) ? 2 * INSH : 10240;
    __shared__ __align__(16) ushortT smem_u[SMU];
    float* pool = (float*)smem_u;

    const int t = threadIdx.x, lane = t & 63, wv = t >> 6;
    const int lc = lane & 15, kb = lane >> 4;
    const int img = blockIdx.z / OCG, g = blockIdx.z % OCG;
    const int x0 = blockIdx.x * 16, y0 = blockIdx.y * 8;
    const float* inb  = in + (size_t)img * inStride;
    const float* in2b = CAT ? (in2 + (size_t)img * inStride) : nullptr;
    const int imgPixBase = img * HW;
    const ushortT* wq0 = wpk + (size_t)g * NCH * 4096;

    f4_t acc[2][4];
    {
        float bz0 = bias[g * 64 +  0 + lc];
        float bz1 = bias[g * 64 + 16 + lc];
        float bz2 = bias[g * 64 + 32 + lc];
        float bz3 = bias[g * 64 + 48 + lc];
        #pragma unroll
        for (int m = 0; m < 2; ++m) {
            acc[m][0] = (f4_t){bz0, bz0, bz0, bz0};
            acc[m][1] = (f4_t){bz1, bz1, bz1, bz1};
            acc[m][2] = (f4_t){bz2, bz2, bz2, bz2};
            acc[m][3] = (f4_t){bz3, bz3, bz3, bz3};
        }
    }
    const int aoff = lc * ICP + kb * 8;
    const int boff = (kb * 64 + lc) * 8;

    #pragma unroll 1
    for (int ic32 = 0; ic32 < IC / 32; ++ic32) {
        __syncthreads();
        // ---- stage chunk: 8-deep loads, paired-channel u32 writes ----
        #pragma unroll 1
        for (int jb = 0; jb < EP; jb += 2048) {
            float v0[8], v1[8];
            #pragma unroll
            for (int u = 0; u < 8; ++u) {
                int j = jb + u * 256 + t;
                v0[u] = 0.f; v1[u] = 0.f;
                if (j < EP) {
                    int ic2 = j / PX;
                    int px  = j - ic2 * PX;
                    int ty = px / TWd, tx = px % TWd;
                    int gy = y0 + ty - P, gx = x0 + tx - P;
                    int ic = ic32 * 32 + 2 * ic2;
                    if (gy >= 0 && gy < WID && gx >= 0 && gx < WID) {
                        const float* s;
                        if (CAT) s = (ic < 64) ? (inb + (size_t)ic * HW)
                                               : (in2b + (size_t)(ic - 64) * HW);
                        else     s = inb + (size_t)ic * HW;
                        float a = s[gy * WID + gx];
                        float b = s[HW + gy * WID + gx];
                        if (LNRM) {
                            int p = imgPixBase + gy * WID + gx;
                            float mm = mu[p], rr = rs[p];
                            a = (a - mm) * rr * lng[ic] + lnb[ic];
                            b = (b - mm) * rr * lng[ic + 1] + lnb[ic + 1];
                        }
                        v0[u] = a; v1[u] = b;
                    }
                }
            }
            #pragma unroll
            for (int u = 0; u < 8; ++u) {
                int j = jb + u * 256 + t;
                if (j < EP) {
                    int ic2 = j / PX;
                    int px  = j - ic2 * PX;
                    ushortT h0 = f2bf(v0[u]), h1 = f2bf(v1[u]);
                    ushortT l0 = f2bf(v0[u] - bf2f(h0));
                    ushortT l1 = f2bf(v1[u] - bf2f(h1));
                    *(unsigned*)&smem_u[px * ICP + 2 * ic2] =
                        (unsigned)h0 | ((unsigned)h1 << 16);
                    *(unsigned*)&smem_u[INSH + px * ICP + 2 * ic2] =
                        (unsigned)l0 | ((unsigned)l1 << 16);
                }
            }
        }
        __syncthreads();
        const ushortT* wqb = wq0 + (size_t)(ic32 * KK) * 4096;
        bf8_t bA[4], lA[4], bB[4], lB[4];
        #pragma unroll
        for (int n = 0; n < 4; ++n) {
            bA[n] = *(const bf8_t*)(wqb + boff + n * 128);
            lA[n] = *(const bf8_t*)(wqb + 2048 + boff + n * 128);
        }
        auto domfma = [&](int kk, bf8_t (&bh)[4], bf8_t (&bl)[4]) {
            const int ky = kk / K, kx = kk % K;
            #pragma unroll
            for (int m = 0; m < 2; ++m) {
                const int row = 2 * wv + m + ky;
                const ushortT* ab = smem_u + (row * TWd + kx) * ICP + aoff;
                bf8_t Ah = *(const bf8_t*)ab;
                bf8_t Al = *(const bf8_t*)(ab + INSH);
                #pragma unroll
                for (int n = 0; n < 4; ++n) {
                    acc[m][n] = __builtin_amdgcn_mfma_f32_16x16x32_bf16(Ah, bh[n], acc[m][n], 0, 0, 0);
                    acc[m][n] = __builtin_amdgcn_mfma_f32_16x16x32_bf16(Ah, bl[n], acc[m][n], 0, 0, 0);
                    acc[m][n] = __builtin_amdgcn_mfma_f32_16x16x32_bf16(Al, bh[n], acc[m][n], 0, 0, 0);
                }
            }
        };
        #pragma unroll 1
        for (int kk = 0; kk + 2 <= KK; kk += 2) {
            const ushortT* w1 = wqb + (size_t)(kk + 1) * 4096;
            #pragma unroll
            for (int n = 0; n < 4; ++n) {
                bB[n] = *(const bf8_t*)(w1 + boff + n * 128);
                lB[n] = *(const bf8_t*)(w1 + 2048 + boff + n * 128);
            }
            domfma(kk, bA, lA);
            const ushortT* w2 = wqb + (size_t)(kk + 2) * 4096;
            #pragma unroll
            for (int n = 0; n < 4; ++n) {
                bA[n] = *(const bf8_t*)(w2 + boff + n * 128);
                lA[n] = *(const bf8_t*)(w2 + 2048 + boff + n * 128);
            }
            domfma(kk + 1, bB, lB);
        }
        domfma(KK - 1, bA, lA);
    }
    if (NHWCOUT) {
        float* ob0 = out + (size_t)img * outStride;
        #pragma unroll
        for (int m = 0; m < 2; ++m) {
            __syncthreads();
            #pragma unroll
            for (int n = 0; n < 4; ++n)
                #pragma unroll
                for (int j = 0; j < 4; ++j) {
                    float v = acc[m][n][j];
                    if (ACT == 1) v = fmaxf(v, 0.f);
                    else if (ACT == 2) v = 1.f / (1.f + __expf(-fmaxf(v, 0.f)));
                    pool[(wv * 16 + kb * 4 + j) * 68 + n * 16 + lc] = v;
                }
            __syncthreads();
            {
                int pix = t >> 2, q = t & 3;
                int y = y0 + 2 * (pix >> 4) + m;
                int x = x0 + (pix & 15);
                float* pr = ob0 + ((size_t)y * WID + x) * 64 + q * 16;
                const float* src = &pool[pix * 68 + q * 16];
                #pragma unroll
                for (int u = 0; u < 4; ++u)
                    *(float4*)&pr[u * 4] = *(const float4*)&src[u * 4];
            }
        }
    } else {
        // ---- direct float4 NCHW store (no LDS, no barriers) ----
        float* ob0 = out + (size_t)img * outStride + (size_t)(g * 64) * HW;
        #pragma unroll
        for (int m = 0; m < 2; ++m) {
            const int y = y0 + 2 * wv + m;
            #pragma unroll
            for (int n = 0; n < 4; ++n) {
                f4_t v = acc[m][n];
                float4 st;
                #pragma unroll
                for (int j = 0; j < 4; ++j) {
                    float vv = v[j];
                    if (ACT == 1) vv = fmaxf(vv, 0.f);
                    else if (ACT == 2) vv = 1.f / (1.f + __expf(-fmaxf(vv, 0.f)));
                    ((float*)&st)[j] = vv;
                }
                *(float4*)&ob0[(size_t)(n * 16 + lc) * HW + (size_t)y * WID + x0 + kb * 4] = st;
            }
        }
    }
}

// ---------------------------------------------------------------------
__global__ __launch_bounds__(256) void ln_stats(
    const float* __restrict__ x, float* __restrict__ mu, float* __restrict__ rs)
{
    const int p = blockIdx.x * 256 + threadIdx.x;
    const int img = p / HW, pp = p - img * HW;
    const float* b = x + (size_t)img * 64 * HW + pp;
    float row[64];
    #pragma unroll
    for (int c = 0; c < 64; ++c) row[c] = b[(size_t)c * HW];
    float s1 = 0.f;
    #pragma unroll
    for (int c = 0; c < 64; ++c) s1 += row[c];
    float m = s1 * (1.f / 64.f);
    float s2 = 0.f;
    #pragma unroll
    for (int c = 0; c < 64; ++c) { float d = row[c] - m; s2 += d * d; }
    mu[p] = m;
    rs[p] = rsqrtf(s2 * (1.f / 64.f) + 1e-5f);
}

// ---------------------------------------------------------------------
__global__ __launch_bounds__(256) void xb1x1(
    const float* __restrict__ x, const float* __restrict__ xbas,
    const float* __restrict__ xo, const float* __restrict__ b1, const float* __restrict__ b2,
    const float* __restrict__ c7w, const float* __restrict__ c7b,
    const float* __restrict__ c8w, const float* __restrict__ c8b,
    float* __restrict__ xbout)
{
    __shared__ __align__(16) float w7s[128 * 36], w8s[128 * 36];
    const int t = threadIdx.x, oh = blockIdx.y;
    for (int i = t; i < 4096; i += 256) {
        int o = i >> 7, ic = i & 127;
        w7s[ic * 36 + o] = c7w[(size_t)(oh * 32 + o) * 128 + ic];
        w8s[ic * 36 + o] = c8w[(size_t)(oh * 32 + o) * 128 + ic];
    }
    __syncthreads();
    const int p = blockIdx.x * 256 + t;
    const int img = p / HW, pp = p - img * HW;
    const float* b1p = b1 + (size_t)img * 128 * HW + pp;
    const float* b2p = b2 + (size_t)img * 128 * HW + pp;
    const float* xp  = x  + (size_t)img * 64 * HW + pp;
    const float* xbp = xbas + (size_t)img * 64 * HW + pp;
    float a7[32], a8[32];
    {
        const float4* c74 = (const float4*)(c7b + oh * 32);
        const float4* c84 = (const float4*)(c8b + oh * 32);
        #pragma unroll
        for (int j4 = 0; j4 < 8; ++j4) {
            float4 v7 = c74[j4], v8 = c84[j4];
            a7[j4*4+0]=v7.x; a7[j4*4+1]=v7.y; a7[j4*4+2]=v7.z; a7[j4*4+3]=v7.w;
            a8[j4*4+0]=v8.x; a8[j4*4+1]=v8.y; a8[j4*4+2]=v8.z; a8[j4*4+3]=v8.w;
        }
    }
    #pragma unroll 4
    for (int ic = 0; ic < 128; ++ic) {
        float tv = b1p[(size_t)ic * HW] * b2p[(size_t)ic * HW];
        float cv = (ic < 64) ? xp[(size_t)ic * HW] : xbp[(size_t)(ic - 64) * HW];
        const float4* w7r = (const float4*)&w7s[ic * 36];
        const float4* w8r = (const float4*)&w8s[ic * 36];
        #pragma unroll
        for (int j4 = 0; j4 < 8; ++j4) {
            float4 v7 = w7r[j4], v8 = w8r[j4];
            a7[j4*4+0] = fmaf(tv, v7.x, a7[j4*4+0]);
            a7[j4*4+1] = fmaf(tv, v7.y, a7[j4*4+1]);
            a7[j4*4+2] = fmaf(tv, v7.z, a7[j4*4+2]);
            a7[j4*4+3] = fmaf(tv, v7.w, a7[j4*4+3]);
            a8[j4*4+0] = fmaf(cv, v8.x, a8[j4*4+0]);
            a8[j4*4+1] = fmaf(cv, v8.y, a8[j4*4+1]);
            a8[j4*4+2] = fmaf(cv, v8.z, a8[j4*4+2]);
            a8[j4*4+3] = fmaf(cv, v8.w, a8[j4*4+3]);
        }
    }
    const float* xop = xo + (size_t)img * 64 * HW + pp;
    float* orow = xbout + (size_t)p * 64 + oh * 32;
    #pragma unroll
    for (int j4 = 0; j4 < 8; ++j4) {
        float4 st;
        st.x = xop[(size_t)(oh*32 + j4*4+0) * HW] * fmaxf(a7[j4*4+0], 0.f) + fmaxf(a8[j4*4+0], 0.f);
        st.y = xop[(size_t)(oh*32 + j4*4+1) * HW] * fmaxf(a7[j4*4+1], 0.f) + fmaxf(a8[j4*4+1], 0.f);
        st.z = xop[(size_t)(oh*32 + j4*4+2) * HW] * fmaxf(a7[j4*4+2], 0.f) + fmaxf(a8[j4*4+2], 0.f);
        st.w = xop[(size_t)(oh*32 + j4*4+3) * HW] * fmaxf(a7[j4*4+3], 0.f) + fmaxf(a8[j4*4+3], 0.f);
        *(float4*)&orow[j4 * 4] = st;
    }
}

// ---------------------------------------------------------------------
// MFMA window attention, Q-in-registers (round 15, unchanged).
// ---------------------------------------------------------------------
__global__ __launch_bounds__(256) void attn(
    const float* __restrict__ xc, const float* __restrict__ xb,
    const float* __restrict__ qkvw, const float* __restrict__ qkvb,
    const float* __restrict__ corw, const float* __restrict__ corb,
    float* __restrict__ aout)
{
    constexpr int QS = 40;
    constexpr int VS = 212;
    __shared__ __align__(16) ushortT Kth[196 * QS];
    __shared__ __align__(16) ushortT Ktl[196 * QS];
    __shared__ __align__(16) ushortT Vth[16 * VS];
    __shared__ __align__(16) ushortT Vtl[16 * VS];
    __shared__ __align__(16) float CB[208];

    const int t = threadIdx.x;
    const int wdw = blockIdx.x >> 2, h = blockIdx.x & 3;
    const int b = wdw >> 8, wl = wdw & 255;
    const int wy = (wl >> 4) * 14, wx = (wl & 15) * 14;
    const int lane = t & 63, wv = t >> 6;
    const int g = lane >> 4, col = lane & 15;

    bf8_t Wqh[2], Wql[2], Wkh[2], Wkl[2], Wvh[2], Wvl[2];
    float qb[4], kb[4], vb[4];
    {
        #pragma unroll
        for (int ks = 0; ks < 2; ++ks) {
            float xv[8];
            const float* wr = qkvw + (h * 16 + col) * 64 + ks * 32 + g * 8;
            *(float4*)&xv[0] = *(const float4*)wr;
            *(float4*)&xv[4] = *(const float4*)(wr + 4);
            cvt8(xv, Wqh[ks], Wql[ks]);
            wr = qkvw + (64 + h * 16 + col) * 64 + ks * 32 + g * 8;
            *(float4*)&xv[0] = *(const float4*)wr;
            *(float4*)&xv[4] = *(const float4*)(wr + 4);
            cvt8(xv, Wkh[ks], Wkl[ks]);
            wr = qkvw + (128 + h * 16 + col) * 64 + ks * 32 + g * 8;
            *(float4*)&xv[0] = *(const float4*)wr;
            *(float4*)&xv[4] = *(const float4*)(wr + 4);
            cvt8(xv, Wvh[ks], Wvl[ks]);
        }
        float4 q4 = *(const float4*)(qkvb + h * 16 + g * 4);
        float4 k4 = *(const float4*)(qkvb + 64 + h * 16 + g * 4);
        float4 v4 = *(const float4*)(qkvb + 128 + h * 16 + g * 4);
        qb[0]=q4.x; qb[1]=q4.y; qb[2]=q4.z; qb[3]=q4.w;
        kb[0]=k4.x; kb[1]=k4.y; kb[2]=k4.z; kb[3]=k4.w;
        vb[0]=v4.x; vb[1]=v4.y; vb[2]=v4.z; vb[3]=v4.w;
    }

    if (t < 208) CB[t] = (t < 196) ? corb[t] : 0.f;
    if (t < 196) {
        unsigned* khr = (unsigned*)&Kth[t * QS];
        unsigned* klr = (unsigned*)&Ktl[t * QS];
        float xw[16];
        const float4* cw4 = (const float4*)(corw + t * 16);
        #pragma unroll
        for (int j = 0; j < 4; ++j) *(float4*)&xw[j * 4] = cw4[j];
        #pragma unroll
        for (int i = 0; i < 8; ++i) {
            ushortT ah = f2bf(xw[2*i]), bh = f2bf(xw[2*i+1]);
            ushortT al = f2bf(xw[2*i] - bf2f(ah)), bl = f2bf(xw[2*i+1] - bf2f(bh));
            khr[8 + i] = (unsigned)ah | ((unsigned)bh << 16);
            klr[8 + i] = (unsigned)al | ((unsigned)bl << 16);
        }
    }

    auto phaseB = [&](int mt) -> f4_t {
        const int row = 16 * mt + col;
        const int pix = (row > 195) ? 195 : row;
        const int rr = pix / 14, cc = pix - (pix / 14) * 14;
        const float* xr = xc + (size_t)((b * 224 + wy + rr) * 224 + wx + cc) * 64;
        f4_t dq = (f4_t){0.f, 0.f, 0.f, 0.f};
        f4_t dk = (f4_t){0.f, 0.f, 0.f, 0.f};
        f4_t dv = (f4_t){0.f, 0.f, 0.f, 0.f};
        #pragma unroll
        for (int ks = 0; ks < 2; ++ks) {
            float xv[8];
            *(float4*)&xv[0] = *(const float4*)(xr + ks * 32 + g * 8);
            *(float4*)&xv[4] = *(const float4*)(xr + ks * 32 + g * 8 + 4);
            bf8_t Xh, Xl;
            cvt8(xv, Xh, Xl);
            dq = __builtin_amdgcn_mfma_f32_16x16x32_bf16(Wqh[ks], Xh, dq, 0, 0, 0);
            dq = __builtin_amdgcn_mfma_f32_16x16x32_bf16(Wqh[ks], Xl, dq, 0, 0, 0);
            dq = __builtin_amdgcn_mfma_f32_16x16x32_bf16(Wql[ks], Xh, dq, 0, 0, 0);
            dk = __builtin_amdgcn_mfma_f32_16x16x32_bf16(Wkh[ks], Xh, dk, 0, 0, 0);
            dk = __builtin_amdgcn_mfma_f32_16x16x32_bf16(Wkh[ks], Xl, dk, 0, 0, 0);
            dk = __builtin_amdgcn_mfma_f32_16x16x32_bf16(Wkl[ks], Xh, dk, 0, 0, 0);
            dv = __builtin_amdgcn_mfma_f32_16x16x32_bf16(Wvh[ks], Xh, dv, 0, 0, 0);
            dv = __builtin_amdgcn_mfma_f32_16x16x32_bf16(Wvh[ks], Xl, dv, 0, 0, 0);
            dv = __builtin_amdgcn_mfma_f32_16x16x32_bf16(Wvl[ks], Xh, dv, 0, 0, 0);
        }
        #pragma unroll
        for (int j = 0; j < 4; ++j) {
            float v = dv[j] + vb[j];
            ushortT hi = f2bf(v);
            Vth[(g * 4 + j) * VS + row] = hi;
            Vtl[(g * 4 + j) * VS + row] = f2bf(v - bf2f(hi));
        }
        if (row < 196) {
            unsigned h0, h1, l0, l1;
            {
                float a = dk[0] + kb[0], bb = dk[1] + kb[1];
                ushortT ah = f2bf(a), bh = f2bf(bb);
                h0 = (unsigned)ah | ((unsigned)bh << 16);
                l0 = (unsigned)f2bf(a - bf2f(ah)) | ((unsigned)f2bf(bb - bf2f(bh)) << 16);
            }
            {
                float a = dk[2] + kb[2], bb = dk[3] + kb[3];
                ushortT ah = f2bf(a), bh = f2bf(bb);
                h1 = (unsigned)ah | ((unsigned)bh << 16);
                l1 = (unsigned)f2bf(a - bf2f(ah)) | ((unsigned)f2bf(bb - bf2f(bh)) << 16);
            }
            uint2 u;
            u.x = h0; u.y = h1; *(uint2*)&Kth[row * QS + g * 4] = u;
            u.x = l0; u.y = l1; *(uint2*)&Ktl[row * QS + g * 4] = u;
        }
        return (f4_t){(dq[0] + qb[0]) * 0.25f, (dq[1] + qb[1]) * 0.25f,
                      (dq[2] + qb[2]) * 0.25f, (dq[3] + qb[3]) * 0.25f};
    };

    f4_t dqs0 = phaseB(wv);
    f4_t dqs1 = phaseB(wv + 4);
    f4_t dqs2 = phaseB(wv + 8);
    f4_t dqs3 = (f4_t){0.f, 0.f, 0.f, 0.f};
    if (wv == 0) dqs3 = phaseB(12);
    __syncthreads();

    auto phaseC = [&](f4_t dqv, int qt) {
        const int row = 16 * qt + col;
        const int pixq = (row > 195) ? 195 : row;
        float q8[8];
        const int sl0 = ((2 * g) & 3) * 16 + col;
        const int sl1 = ((2 * g + 1) & 3) * 16 + col;
        q8[0] = __shfl(dqv[0], sl0); q8[1] = __shfl(dqv[1], sl0);
        q8[2] = __shfl(dqv[2], sl0); q8[3] = __shfl(dqv[3], sl0);
        q8[4] = __shfl(dqv[0], sl1); q8[5] = __shfl(dqv[1], sl1);
        q8[6] = __shfl(dqv[2], sl1); q8[7] = __shfl(dqv[3], sl1);
        if (g >= 2) {
            const int rr = pixq / 14, cc = pixq - (pixq / 14) * 14;
            const float* xr = xb + (size_t)((b * 224 + wy + rr) * 224 + wx + cc) * 64
                            + h * 16 + (g & 1) * 8;
            *(float4*)&q8[0] = *(const float4*)xr;
            *(float4*)&q8[4] = *(const float4*)(xr + 4);
        }
        bf8_t Bhf, Blf;
        cvt8(q8, Bhf, Blf);
        f4_t s[13];
        __builtin_amdgcn_s_setprio(1);
        #pragma unroll
        for (int kt = 0; kt < 13; ++kt) {
            const int krow = (16 * kt + col > 195) ? 195 : (16 * kt + col);
            const bf8_t Ahf = *(const bf8_t*)&Kth[krow * QS + g * 8];
            const bf8_t Alf = *(const bf8_t*)&Ktl[krow * QS + g * 8];
            f4_t a = (f4_t){0.f, 0.f, 0.f, 0.f};
            a = __builtin_amdgcn_mfma_f32_16x16x32_bf16(Ahf, Bhf, a, 0, 0, 0);
            a = __builtin_amdgcn_mfma_f32_16x16x32_bf16(Ahf, Blf, a, 0, 0, 0);
            a = __builtin_amdgcn_mfma_f32_16x16x32_bf16(Alf, Bhf, a, 0, 0, 0);
            const f4_t cb4 = *(const f4_t*)&CB[16 * kt + g * 4];
            s[kt] = a + cb4;
        }
        __builtin_amdgcn_s_setprio(0);
        if (g > 0) { s[12][0] = -3e38f; s[12][1] = -3e38f; s[12][2] = -3e38f; s[12][3] = -3e38f; }
        float mrow = -3e38f;
        #pragma unroll
        for (int kt = 0; kt < 13; ++kt)
            #pragma unroll
            for (int j = 0; j < 4; ++j) mrow = fmaxf(mrow, s[kt][j]);
        mrow = fmaxf(mrow, __shfl_xor(mrow, 16));
        mrow = fmaxf(mrow, __shfl_xor(mrow, 32));
        float lsum = 0.f;
        bf4_t ph[13], pl[13];
        #pragma unroll
        for (int kt = 0; kt < 13; ++kt) {
            #pragma unroll
            for (int j = 0; j < 4; ++j) {
                float p = __expf(s[kt][j] - mrow);
                lsum += p;
                ushortT hi = f2bf(p);
                ph[kt][j] = (short)hi;
                pl[kt][j] = (short)f2bf(p - bf2f(hi));
            }
        }
        lsum += __shfl_xor(lsum, 16);
        lsum += __shfl_xor(lsum, 32);
        f4_t o = (f4_t){0.f, 0.f, 0.f, 0.f};
        __builtin_amdgcn_s_setprio(1);
        #pragma unroll
        for (int kt = 0; kt < 13; ++kt) {
            const bf4_t vh = *(const bf4_t*)&Vth[col * VS + 16 * kt + g * 4];
            const bf4_t vl = *(const bf4_t*)&Vtl[col * VS + 16 * kt + g * 4];
            o = __builtin_amdgcn_mfma_f32_16x16x16bf16_1k(vh, ph[kt], o, 0, 0, 0);
            o = __builtin_amdgcn_mfma_f32_16x16x16bf16_1k(vl, ph[kt], o, 0, 0, 0);
            o = __builtin_amdgcn_mfma_f32_16x16x16bf16_1k(vh, pl[kt], o, 0, 0, 0);
        }
        __builtin_amdgcn_s_setprio(0);
        const int pix = 16 * qt + col;
        if (pix < 196) {
            const float inv = 1.f / lsum;
            const int rr = pix / 14, cc = pix % 14;
            const size_t pixIdx = (size_t)((b * 224 + wy + rr) * 224 + wx + cc);
            float4 st = { o[0] * inv, o[1] * inv, o[2] * inv, o[3] * inv };
            *(float4*)&aout[pixIdx * 64 + h * 16 + g * 4] = st;
        }
    };

    phaseC(dqs0, wv);
    phaseC(dqs1, wv + 4);
    phaseC(dqs2, wv + 8);
    if (wv == 0) phaseC(dqs3, 12);
}

// ---------------------------------------------------------------------
// MFMA proj+LN+MLP (round 16, unchanged).
// ---------------------------------------------------------------------
__global__ __launch_bounds__(256) void mlpmf(
    const float* __restrict__ aout, const ushortT* __restrict__ pk,
    const float* __restrict__ pbias,
    const float* __restrict__ lng, const float* __restrict__ lnb,
    const float* __restrict__ fc1b, const float* __restrict__ fc2b,
    float* __restrict__ out)
{
    const int t = threadIdx.x, lane = t & 63, wv = t >> 6;
    const int gq = lane >> 4, col = lane & 15;
    const int p0 = (blockIdx.x * 4 + wv) * 16;
    const ushortT* pk1 = pk;
    const ushortT* pk2 = pk + 8192;
    const ushortT* pk3 = pk + 24576;

    f4_t S[4];
    #pragma unroll
    for (int n = 0; n < 4; ++n) {
        float4 b4 = *(const float4*)(pbias + n * 16 + gq * 4);
        S[n] = (f4_t){b4.x, b4.y, b4.z, b4.w};
    }
    const float* xr = aout + (size_t)(p0 + col) * 64;
    #pragma unroll
    for (int ks = 0; ks < 2; ++ks) {
        float xv[8];
        *(float4*)&xv[0] = *(const float4*)(xr + ks * 32 + gq * 8);
        *(float4*)&xv[4] = *(const float4*)(xr + ks * 32 + gq * 8 + 4);
        bf8_t Xh, Xl;
        cvt8(xv, Xh, Xl);
        #pragma unroll
        for (int n = 0; n < 4; ++n) {
            const ushortT* a = pk1 + (size_t)(n * 2 + ks) * 1024 + lane * 8;
            bf8_t Ah = *(const bf8_t*)a;
            bf8_t Al = *(const bf8_t*)(a + 512);
            S[n] = __builtin_amdgcn_mfma_f32_16x16x32_bf16(Ah, Xh, S[n], 0, 0, 0);
            S[n] = __builtin_amdgcn_mfma_f32_16x16x32_bf16(Ah, Xl, S[n], 0, 0, 0);
            S[n] = __builtin_amdgcn_mfma_f32_16x16x32_bf16(Al, Xh, S[n], 0, 0, 0);
        }
    }
    float sum = 0.f;
    #pragma unroll
    for (int n = 0; n < 4; ++n)
        #pragma unroll
        for (int j = 0; j < 4; ++j) sum += S[n][j];
    sum += __shfl_xor(sum, 16);
    sum += __shfl_xor(sum, 32);
    float mean = sum * (1.f / 64.f);
    float var = 0.f;
    #pragma unroll
    for (int n = 0; n < 4; ++n)
        #pragma unroll
        for (int j = 0; j < 4; ++j) { float d = S[n][j] - mean; var += d * d; }
    var += __shfl_xor(var, 16);
    var += __shfl_xor(var, 32);
    float rstd = rsqrtf(var * (1.f / 64.f) + 1e-5f);
    bf4_t Nh[4], Nl[4];
    #pragma unroll
    for (int n = 0; n < 4; ++n) {
        float4 g4 = *(const float4*)(lng + n * 16 + gq * 4);
        float4 b4 = *(const float4*)(lnb + n * 16 + gq * 4);
        float nv0 = (S[n][0] - mean) * rstd * g4.x + b4.x;
        float nv1 = (S[n][1] - mean) * rstd * g4.y + b4.y;
        float nv2 = (S[n][2] - mean) * rstd * g4.z + b4.z;
        float nv3 = (S[n][3] - mean) * rstd * g4.w + b4.w;
        ushortT h0 = f2bf(nv0), h1 = f2bf(nv1), h2 = f2bf(nv2), h3 = f2bf(nv3);
        Nh[n][0] = (short)h0; Nh[n][1] = (short)h1; Nh[n][2] = (short)h2; Nh[n][3] = (short)h3;
        Nl[n][0] = (short)f2bf(nv0 - bf2f(h0));
        Nl[n][1] = (short)f2bf(nv1 - bf2f(h1));
        Nl[n][2] = (short)f2bf(nv2 - bf2f(h2));
        Nl[n][3] = (short)f2bf(nv3 - bf2f(h3));
    }
    bf4_t Gh[8], Gl[8];
    #pragma unroll
    for (int o = 0; o < 8; ++o) {
        float4 b4 = *(const float4*)(fc1b + o * 16 + gq * 4);
        f4_t hacc = (f4_t){b4.x, b4.y, b4.z, b4.w};
        #pragma unroll
        for (int n = 0; n < 4; ++n) {
            const ushortT* a = pk2 + (size_t)(o * 4 + n) * 512 + lane * 4;
            bf4_t Ah = *(const bf4_t*)a;
            bf4_t Al = *(const bf4_t*)(a + 256);
            hacc = __builtin_amdgcn_mfma_f32_16x16x16bf16_1k(Ah, Nh[n], hacc, 0, 0, 0);
            hacc = __builtin_amdgcn_mfma_f32_16x16x16bf16_1k(Ah, Nl[n], hacc, 0, 0, 0);
            hacc = __builtin_amdgcn_mfma_f32_16x16x16bf16_1k(Al, Nh[n], hacc, 0, 0, 0);
        }
        #pragma unroll
        for (int j = 0; j < 4; ++j) {
            float hv = hacc[j];
            float gl = 0.5f * hv * (1.f + erff(hv * 0.70710678118f));
            ushortT hi = f2bf(gl);
            Gh[o][j] = (short)hi;
            Gl[o][j] = (short)f2bf(gl - bf2f(hi));
        }
    }
    const int img = p0 / HW, pp = p0 - img * HW;
    float* ob = out + (size_t)img * 64 * HW + pp + col;
    #pragma unroll
    for (int o2 = 0; o2 < 4; ++o2) {
        float4 b4 = *(const float4*)(fc2b + o2 * 16 + gq * 4);
        f4_t oacc = (f4_t){b4.x, b4.y, b4.z, b4.w};
        #pragma unroll
        for (int k2 = 0; k2 < 8; ++k2) {
            const ushortT* a = pk3 + (size_t)(o2 * 8 + k2) * 512 + lane * 4;
            bf4_t Ah = *(const bf4_t*)a;
            bf4_t Al = *(const bf4_t*)(a + 256);
            oacc = __builtin_amdgcn_mfma_f32_16x16x16bf16_1k(Ah, Gh[k2], oacc, 0, 0, 0);
            oacc = __builtin_amdgcn_mfma_f32_16x16x16bf16_1k(Ah, Gl[k2], oacc, 0, 0, 0);
            oacc = __builtin_amdgcn_mfma_f32_16x16x16bf16_1k(Al, Gh[k2], oacc, 0, 0, 0);
        }
        #pragma unroll
        for (int j = 0; j < 4; ++j) {
            int och = o2 * 16 + gq * 4 + j;
            ob[(size_t)och * HW] = S[o2][j] + oacc[j];
        }
    }
}

// ---------------------------------------------------------------------
extern "C" void kernel_launch(void* const* d_in, const int* in_sizes, int n_in,
                              void* d_out, int out_size, void* d_ws, size_t ws_size,
                              hipStream_t stream)
{
    (void)in_sizes; (void)n_in; (void)out_size;
    const float* x      = (const float*)d_in[0];
    const float* xbasic = (const float*)d_in[1];
    const float* c1w  = (const float*)d_in[2];  const float* c1b  = (const float*)d_in[3];
    const float* c2w  = (const float*)d_in[4];  const float* c2b  = (const float*)d_in[5];
    const float* c3w  = (const float*)d_in[6];  const float* c3b  = (const float*)d_in[7];
    const float* c4w  = (const float*)d_in[8];  const float* c4b  = (const float*)d_in[9];
    const float* c5w  = (const float*)d_in[10]; const float* c5b  = (const float*)d_in[11];
    const float* c6w  = (const float*)d_in[12]; const float* c6b  = (const float*)d_in[13];
    const float* c7w  = (const float*)d_in[14]; const float* c7b  = (const float*)d_in[15];
    const float* c8w  = (const float*)d_in[16]; const float* c8b  = (const float*)d_in[17];
    const float* qk1w = (const float*)d_in[18]; const float* qk1b = (const float*)d_in[19];
    const float* n1g  = (const float*)d_in[20]; const float* n1b  = (const float*)d_in[21];
    const float* qkvw = (const float*)d_in[22]; const float* qkvb = (const float*)d_in[23];
    const float* corw = (const float*)d_in[24]; const float* corb = (const float*)d_in[25];
    const float* prjw = (const float*)d_in[26]; const float* prjb = (const float*)d_in[27];
    const float* n2g  = (const float*)d_in[28]; const float* n2b  = (const float*)d_in[29];
    const float* f1w  = (const float*)d_in[30]; const float* f1b  = (const float*)d_in[31];
    const float* f2w  = (const float*)d_in[32]; const float* f2b  = (const float*)d_in[33];

    float* ws = (float*)d_ws;
    const size_t SCR0 = 26836992ull;
    const size_t need4 = (SCR0 + 4ull * 19267584ull) * 4ull;  // 415.6 MB
    const size_t need2 = (SCR0 + 2ull * 19267584ull) * 4ull;  // 261.5 MB
    const int CS = (ws_size >= need4) ? 4 : (ws_size >= need2) ? 2 : 1;
    const int nch = 4 / CS;

    float* XC = ws;
    float* XB = ws + 12845056;
    float* MU = ws + 25690112;
    float* RS = ws + 25890816;
    ushortT* WP = (ushortT*)(ws + 26091520);
    float* A  = ws + SCR0;
    float* XO = A + (size_t)CS * 9633792;
    float* B1 = XO + (size_t)CS * 3211264;
    float* B2 = A;          // alias (A dead after c4)
    float* AOUT = A;        // alias (conv scratch dead at attn time)
    ushortT* WQ1 = (ushortT*)B1;  // transient: qkv1 packed weights (73728 u16)
    ushortT* PM  = (ushortT*)MU;  // mlp packed weights (40960 u16; MU dead after qkv1)

    const size_t o1 = 0, o2 = 73728, o3 = 278528, o4 = 679936, o5 = 901120, o6 = 1196032;

    ln_stats<<<784, 256, 0, stream>>>(x, MU, RS);

    // ---- pre-pack conv weights ----
    {
        auto PK = [&](const float* w, ushortT* dst, int K, int IC, int OC) {
            int tot = OC * IC * K * K;
            packw<<<(tot + 255) / 256, 256, 0, stream>>>(w, dst, K, IC, OC, tot);
        };
        PK(qk1w, WQ1, 3, 64, 64);
        PK(c1w, WP + o1, 3, 64, 64);
        PK(c2w, WP + o2, 5, 64, 64);
        PK(c3w, WP + o3, 7, 64, 64);
        PK(c4w, WP + o4, 3, 192, 64);
        PK(c5w, WP + o5, 3, 128, 128);
        PK(c6w, WP + o6, 3, 128, 128);
    }

    // ---- qkv1: LN-fused MFMA conv, NHWC out (consumes MU/RS) ----
    mfconv<3, 64, 64, 0, false, true, true><<<dim3(14, 28, 4), 256, 0, stream>>>(
        x, nullptr, WQ1, qk1b, MU, RS, n1g, n1b, XC, 64 * HW, HW * 64);

    // ---- pack MLP weights into MU (dead now) ----
    packa32<<<16, 256, 0, stream>>>(prjw, PM, 64, 4096);
    packa16<<<32, 256, 0, stream>>>(f1w, PM + 8192, 64, 8192);
    packa16<<<32, 256, 0, stream>>>(f2w, PM + 24576, 128, 8192);

    for (int ch = 0; ch < nch; ++ch) {
        const float* xi  = x      + (size_t)ch * CS * 64 * HW;
        const float* xbi = xbasic + (size_t)ch * CS * 64 * HW;
        mfconv3<<<dim3(14, 28, CS), 256, 0, stream>>>(
            xi, WP + o1, WP + o2, WP + o3, c1b, c2b, c3b, A, 64 * HW, 192 * HW);
        mfconv<3, 192, 64, 1, false, false, false><<<dim3(14, 28, CS), 256, 0, stream>>>(
            A, nullptr, WP + o4, c4b, nullptr, nullptr, nullptr, nullptr, XO, 192 * HW, 64 * HW);
        mfconv<3, 128, 128, 1, true, false, false><<<dim3(14, 28, CS * 2), 256, 0, stream>>>(
            xi, xbi, WP + o5, c5b, nullptr, nullptr, nullptr, nullptr, B1, 64 * HW, 128 * HW);
        mfconv<3, 128, 128, 2, false, false, false><<<dim3(14, 28, CS * 2), 256, 0, stream>>>(
            B1, nullptr, WP + o6, c6b, nullptr, nullptr, nullptr, nullptr, B2, 128 * HW, 128 * HW);
        xb1x1<<<dim3(CS * 196, 2), 256, 0, stream>>>(
            xi, xbi, XO, B1, B2, c7w, c7b, c8w, c8b, XB + (size_t)ch * CS * HW * 64);
    }

    attn<<<4096, 256, 0, stream>>>(XC, XB, qkvw, qkvb, corw, corb, AOUT);
    mlpmf<<<3136, 256, 0, stream>>>(AOUT, PM, prjb, n2g, n2b, f1b, f2b,
                                    (float*)d_out);
}